// Round 19
// baseline (206.941 us; speedup 1.0000x reference)
//
#include <hip/hip_runtime.h>
#include <hip/hip_bf16.h>
#include <stdint.h>

#define N_NODES   100000
#define N_EVENTS  50000
#define N_COMM    256
#define DIM_M     128
#define K_TOT     576   // 448 msg + 128 mem
#define GCOLS     512
#define INV2PI    0.15915494309189535f
#define XB_GRID   2048
#define WCONV_BLOCKS ((GCOLS * K_TOT + 255) / 256)   // 1152
#define COPY_BLOCKS  512
#define NBLK      ((2 * N_EVENTS + 255) / 256)       // 391

typedef float f32x4 __attribute__((ext_vector_type(4)));
typedef short s16x8 __attribute__((ext_vector_type(8)));
typedef short s16x4 __attribute__((ext_vector_type(4)));

// ---------------- ws layout ----------------
#define KEYS_OFF   0                      // u64[N]
#define CNT_OFF    800000                 // u32
#define LIST_OFF   800008                 // i32[N] -> ends 1200008
#define EINFO_OFF  1200064                // int4[N] = 1.6MB -> ends 2800064
#define WT_OFF     2800128                // bf16 [512][576] -> ends 3389952
#define X_ROWS     100096
#define X_OFF      3390208                // bf16 [100096][576] -> ends 118700800
// comm scratch OVERLAYS X region (X dead before comm runs)
#define PART_M_OFF X_OFF                  // f32 [512][32768] = 67.1MB (permuted)
#define CT_NCH     512
#define CT_CPN     196
#define TMP2_OFF   (PART_M_OFF + 67108864)
// scan scratch overlays TMP2 (scan done long before comm2a writes tmp2)
#define BCNT_OFF   TMP2_OFF
#define BOFF_OFF   (TMP2_OFF + 2048)
// fallback path:
#define WT_F_OFF   1200640
#define TENC_OFF   1790464
#define PART_F_OFF 14594560
#define BCNT_F_OFF PART_F_OFF
#define BOFF_F_OFF (PART_F_OFF + 2048)

__device__ inline unsigned short f2bf(float x) {
    union { float f; unsigned u; } v; v.f = x;
    unsigned r = v.u + 0x7FFFu + ((v.u >> 16) & 1u);
    return (unsigned short)(r >> 16);
}
__device__ inline float bf2f(unsigned short u) {
    union { unsigned u; float f; } v; v.u = ((unsigned)u) << 16;
    return v.f;
}
__device__ inline float cos_rev(float rev) {
    float fr = rev - floorf(rev);
#if __has_builtin(__builtin_amdgcn_cosf)
    return __builtin_amdgcn_cosf(fr);
#else
    return cosf(fr * 6.283185307179586f);
#endif
}
__device__ inline float sigmoid_f(float x) { return 1.0f / (1.0f + __expf(-x)); }
__device__ inline float tanh_f(float x) {
    float t = __expf(2.0f * x);
    return 1.0f - 2.0f / (t + 1.0f);
}
__device__ inline s16x8 pack_bf8(float4 a, float4 b) {
    s16x8 v;
    v[0] = (short)f2bf(a.x); v[1] = (short)f2bf(a.y);
    v[2] = (short)f2bf(a.z); v[3] = (short)f2bf(a.w);
    v[4] = (short)f2bf(b.x); v[5] = (short)f2bf(b.y);
    v[6] = (short)f2bf(b.z); v[7] = (short)f2bf(b.w);
    return v;
}

// ---------- phase 1 ----------
__global__ __launch_bounds__(256) void k_agg(const int* __restrict__ src,
                                             const int* __restrict__ dst,
                                             const int* __restrict__ t,
                                             unsigned long long* __restrict__ keys) {
    int i = blockIdx.x * 256 + threadIdx.x;
    if (i >= 2 * N_EVENTS) return;
    int e = (i < N_EVENTS) ? i : i - N_EVENTS;
    int node = (i < N_EVENTS) ? src[i] : dst[e];
    unsigned long long key =
        ((unsigned long long)(unsigned)t[e] << 32) | (unsigned)(i + 1);
    atomicMax(&keys[node], key);
}

// ---------- phase 2a: flag winners per 256-event block ----------
__global__ __launch_bounds__(256) void k_flag(const int* __restrict__ src,
                                              const int* __restrict__ dst,
                                              const unsigned long long* __restrict__ keys,
                                              unsigned* __restrict__ bcount) {
    const int i = blockIdx.x * 256 + threadIdx.x;
    int win = 0;
    if (i < 2 * N_EVENTS) {
        int e = (i < N_EVENTS) ? i : i - N_EVENTS;
        int node = (i < N_EVENTS) ? src[i] : dst[e];
        win = ((unsigned)(keys[node] & 0xffffffffull) == (unsigned)(i + 1));
    }
    __shared__ unsigned cnt_s;
    if (threadIdx.x == 0) cnt_s = 0;
    __syncthreads();
    unsigned long long m = __ballot(win);
    if ((threadIdx.x & 63) == 0) atomicAdd(&cnt_s, (unsigned)__popcll(m));
    __syncthreads();
    if (threadIdx.x == 0) bcount[blockIdx.x] = cnt_s;
}

// ---------- phase 2b: exclusive scan of block counts (1 block) ----------
__global__ __launch_bounds__(512) void k_scan(const unsigned* __restrict__ bcount,
                                              unsigned* __restrict__ boff,
                                              unsigned int* __restrict__ cnt) {
    __shared__ unsigned s[512];
    const int tid = threadIdx.x;
    unsigned v = (tid < NBLK) ? bcount[tid] : 0;
    s[tid] = v;
    __syncthreads();
    for (int off = 1; off < 512; off <<= 1) {
        unsigned tv = (tid >= off) ? s[tid - off] : 0;
        __syncthreads();
        s[tid] += tv;
        __syncthreads();
    }
    if (tid < NBLK) boff[tid] = s[tid] - v;
    if (tid == NBLK - 1) *cnt = s[tid];
}

// ---------- phase 2c: emit rows in event-block order ----------
__global__ __launch_bounds__(256) void k_emit(const int* __restrict__ src,
                                              const int* __restrict__ dst,
                                              const int* __restrict__ t,
                                              const int* __restrict__ last_update,
                                              const unsigned long long* __restrict__ keys,
                                              const unsigned* __restrict__ boff,
                                              int* __restrict__ list,
                                              int4* __restrict__ einfo) {
    const int i = blockIdx.x * 256 + threadIdx.x;
    __shared__ unsigned lcnt;
    if (threadIdx.x == 0) lcnt = 0;
    __syncthreads();
    if (i < 2 * N_EVENTS) {
        const int e = (i < N_EVENTS) ? i : i - N_EVENTS;
        const int node = (i < N_EVENTS) ? src[i] : dst[e];
        if ((unsigned)(keys[node] & 0xffffffffull) == (unsigned)(i + 1)) {
            unsigned r = atomicAdd(&lcnt, 1u);
            unsigned pos = boff[blockIdx.x] + r;
            list[pos] = node;
            const float dt = (float)(t[e] - last_update[node]);
            einfo[pos] = make_int4(node, i, __float_as_int(dt), 0);
        }
    }
}

// ---------- phase 3a: build X (8 thr/row, 16 gathers in flight) + wconv + copy ----------
__global__ __launch_bounds__(256) void k_xbuild(
    const unsigned long long* __restrict__ keys,
    const unsigned int* __restrict__ cnt,
    const int4* __restrict__ einfo,
    const float* __restrict__ event_feat,
    const float* __restrict__ src_embeds,
    const float* __restrict__ dst_embeds,
    const float* __restrict__ mem,
    const float* __restrict__ w_time,
    const float* __restrict__ b_time,
    const float* __restrict__ W_ih,
    const float* __restrict__ W_hh,
    unsigned short* __restrict__ Wt,
    unsigned short* __restrict__ X,
    float* __restrict__ out) {
    if (blockIdx.x >= XB_GRID + WCONV_BLOCKS) {   // ---- copy-through ----
        const int b = blockIdx.x - (XB_GRID + WCONV_BLOCKS);
        for (int idx = b * 256 + threadIdx.x; idx < N_NODES * 32;
             idx += COPY_BLOCKS * 256) {
            const int n = idx >> 5;
            if (keys[n] == 0ULL)
                ((float4*)out)[idx] = ((const float4*)mem)[idx];
        }
        return;
    }
    if (blockIdx.x >= XB_GRID) {   // ---- fused weight conversion ----
        int idx = (blockIdx.x - XB_GRID) * 256 + threadIdx.x;
        if (idx >= GCOLS * K_TOT) return;
        int col2 = idx / K_TOT, k = idx % K_TOT;
        int mh = col2 >> 8, rem = col2 & 255;
        int g = rem >> 6, m = mh * 64 + (rem & 63);
        float v;
        if (g == 0)      v = (k < 448) ? W_ih[(size_t)k * 384 + m]
                                       : W_hh[(size_t)(k - 448) * 384 + m];
        else if (g == 1) v = (k < 448) ? W_ih[(size_t)k * 384 + 128 + m]
                                       : W_hh[(size_t)(k - 448) * 384 + 128 + m];
        else if (g == 2) v = (k < 448) ? W_ih[(size_t)k * 384 + 256 + m] : 0.0f;
        else             v = (k < 448) ? 0.0f : W_hh[(size_t)(k - 448) * 384 + 256 + m];
        Wt[idx] = f2bf(v);
        return;
    }
    // ---- X build: 8 threads per row, slots s = j*8 + l8, j = 0..8 ----
    const unsigned c = *cnt;
    const unsigned cpad = (c + 127u) & ~127u;
    const int l8 = threadIdx.x & 7;
    const int off = l8 * 8;
    for (unsigned row = (blockIdx.x * 256u + threadIdx.x) >> 3; row < cpad;
         row += (XB_GRID * 256u) >> 3) {
        unsigned short* xp = X + (size_t)row * K_TOT + off;
        if (row >= c) {
            s16x8 z;
#pragma unroll
            for (int q = 0; q < 8; ++q) z[q] = 0;
#pragma unroll
            for (int j = 0; j < 9; ++j) *(s16x8*)(xp + j * 64) = z;
            continue;
        }
        const int4 ei = einfo[row];
        const int ia = ei.y;
        const int e = (ia < N_EVENTS) ? ia : ia - N_EVENTS;
        const float* sp = src_embeds + (size_t)e * 128;
        const float* dp = dst_embeds + (size_t)e * 128;
        const float* pe_s = (ia < N_EVENTS) ? sp : dp;
        const float* pe_d = (ia < N_EVENTS) ? dp : sp;
        const float* pe_f = event_feat + (size_t)e * 128;
        const float* pm   = mem + (size_t)ei.x * 128;
        const float* ps[8] = {pe_s, pe_s + 64, pe_d, pe_d + 64,
                              pe_f, pe_f + 64, pm,   pm + 64};
        float4 d0[8], d1[8];
#pragma unroll
        for (int j = 0; j < 8; ++j) {
            d0[j] = *(const float4*)(ps[j] + off);
            d1[j] = *(const float4*)(ps[j] + off + 4);
        }
        const float dt = __int_as_float(ei.z);
        s16x8 tv;
#pragma unroll
        for (int q = 0; q < 8; ++q) {
            float rev = fmaf(dt, w_time[off + q] * INV2PI, b_time[off + q] * INV2PI);
            tv[q] = (short)f2bf(cos_rev(rev));
        }
#pragma unroll
        for (int j = 0; j < 6; ++j)
            *(s16x8*)(xp + j * 64) = pack_bf8(d0[j], d1[j]);
        *(s16x8*)(xp + 6 * 64) = tv;
        *(s16x8*)(xp + 7 * 64) = pack_bf8(d0[6], d1[6]);
        *(s16x8*)(xp + 8 * 64) = pack_bf8(d0[7], d1[7]);
    }
}

// ---------- phase 3b: MFMA GEMM, BK=32, 2 LDS bufs -> 3 blocks/CU (m97 pattern) ----------
__global__ __launch_bounds__(512) void k_gemm2(
    const unsigned int* __restrict__ cnt,
    const int* __restrict__ list,
    const unsigned short* __restrict__ X,
    const unsigned short* __restrict__ Wt,
    const float* __restrict__ b_ih,
    const float* __restrict__ b_hh,
    float* __restrict__ out) {
    __shared__ unsigned short As[2][128][32];   // 16 KB
    __shared__ unsigned short Bs[2][256][32];   // 32 KB
    __shared__ int Ls[128];

    const unsigned c = *cnt;
    const int rb = blockIdx.x >> 1;
    const int mh = blockIdx.x & 1;
    const int base = rb * 128;
    if ((unsigned)base >= c) return;
    const int tid = threadIdx.x;
    const int w = tid >> 6, l = tid & 63;
    const int lr = l & 15, lk = l >> 4;
    const int wm = w >> 2, wn = w & 3;

    if (tid < 128)
        Ls[tid] = ((unsigned)(base + tid) < c) ? list[base + tid] : 0;

    const int mcol = mh * 64 + wn * 16 + lr;

    unsigned short hreg[16];
#pragma unroll
    for (int rt = 0; rt < 4; ++rt)
#pragma unroll
        for (int reg = 0; reg < 4; ++reg) {
            const int r = wm * 64 + rt * 16 + lk * 4 + reg;
            hreg[rt * 4 + reg] = X[(size_t)(base + r) * K_TOT + 448 + mcol];
        }

    const int srow = tid >> 2;
    const int sd = tid & 3;
    const int ssl = (sd ^ ((srow >> 1) & 3)) << 3;
    const unsigned short* gA  = X  + (size_t)(base + srow) * K_TOT + ssl;
    const unsigned short* gB0 = Wt + (size_t)(mh * 256 + srow) * K_TOT + ssl;
    const unsigned short* gB1 = Wt + (size_t)(mh * 256 + 128 + srow) * K_TOT + ssl;

#define GLD(SRC, DST) __builtin_amdgcn_global_load_lds( \
        (const __attribute__((address_space(1))) unsigned int*)(SRC), \
        (__attribute__((address_space(3))) unsigned int*)(DST), 16, 0, 0)

    auto stage = [&](int ch, int buf) {
        GLD(gA  + ch * 32, &As[buf][w * 16][0]);
        GLD(gB0 + ch * 32, &Bs[buf][w * 16][0]);
        GLD(gB1 + ch * 32, &Bs[buf][128 + w * 16][0]);
    };

    f32x4 acc[4][4];
#pragma unroll
    for (int rt = 0; rt < 4; ++rt)
#pragma unroll
        for (int i = 0; i < 4; ++i) acc[rt][i] = (f32x4){0.f, 0.f, 0.f, 0.f};

    stage(0, 0);
    __syncthreads();   // chunk 0 resident (hreg/Ls also drained)

#pragma unroll
    for (int ch = 0; ch < 18; ++ch) {
        const int buf = ch & 1;
        if (ch < 17) stage(ch + 1, buf ^ 1);   // overlap next-chunk DMA with compute
        __builtin_amdgcn_s_setprio(1);
        s16x8 a[4];
#pragma unroll
        for (int rt = 0; rt < 4; ++rt) {
            const int r = wm * 64 + rt * 16 + lr;
            const int sl = lk ^ ((r >> 1) & 3);
            a[rt] = *(const s16x8*)&As[buf][r][sl << 3];
        }
#pragma unroll
        for (int i = 0; i < 4; ++i) {
            const int cl = i * 64 + wn * 16 + lr;
            const int slb = lk ^ ((cl >> 1) & 3);
            s16x8 b = *(const s16x8*)&Bs[buf][cl][slb << 3];
#pragma unroll
            for (int rt = 0; rt < 4; ++rt)
                acc[rt][i] = __builtin_amdgcn_mfma_f32_16x16x32_bf16(
                    a[rt], b, acc[rt][i], 0, 0, 0);
        }
        __builtin_amdgcn_s_setprio(0);
        if (ch < 17) __syncthreads();   // drain stage(ch+1), release buf for ch+2
    }

    const float b_r  = b_ih[mcol] + b_hh[mcol];
    const float b_z  = b_ih[128 + mcol] + b_hh[128 + mcol];
    const float b_xn = b_ih[256 + mcol];
    const float b_hn = b_hh[256 + mcol];
#pragma unroll
    for (int rt = 0; rt < 4; ++rt) {
#pragma unroll
        for (int reg = 0; reg < 4; ++reg) {
            const int r = wm * 64 + rt * 16 + lk * 4 + reg;
            const int grow = base + r;
            if ((unsigned)grow < c) {
                const int node = Ls[r];
                const float h = bf2f(hreg[rt * 4 + reg]);
                float rr = sigmoid_f(acc[rt][0][reg] + b_r);
                float zz = sigmoid_f(acc[rt][1][reg] + b_z);
                float nn = tanh_f(acc[rt][2][reg] + b_xn + rr * (acc[rt][3][reg] + b_hn));
                out[(size_t)node * 128 + mcol] = (1.0f - zz) * nn + zz * h;
            }
        }
    }
#undef GLD
}

// ---------- phase 4 (fallback only): copy-through ----------
__global__ __launch_bounds__(256) void k_copy(const unsigned long long* __restrict__ keys,
                                              const float* __restrict__ nm,
                                              float* __restrict__ out) {
    int idx = blockIdx.x * 256 + threadIdx.x;
    int n = idx >> 5;
    if (n >= N_NODES) return;
    if (keys[n] != 0ULL) return;
    ((float4*)out)[idx] = ((const float4*)nm)[idx];
}

// ---------- phase 5a: comm (round-11 version, unchanged) ----------
__global__ __launch_bounds__(512) void k_comm_t(const float* __restrict__ inc,
                                                const float* __restrict__ nm,
                                                float* __restrict__ partials) {
    __shared__ unsigned short T[2][12288];

    const int bid = blockIdx.x;
    const int n0 = bid * CT_CPN;
    const int n1 = min(N_NODES, n0 + CT_CPN);
    const int ng = (n1 - n0 + 31) >> 5;
    const int tid = threadIdx.x;
    const int w = tid >> 6, l = tid & 63;
    const int lr = l & 15, lk = l >> 4;

    float vi[4][4];
    float vm[4][2];

    auto load_chunk = [&](int g) {
        const int nb = n0 + g * 32 + w * 4;
#pragma unroll
        for (int ri = 0; ri < 4; ++ri) {
            const int n = nb + ri;
            const bool ok = n < n1;
#pragma unroll
            for (int j = 0; j < 4; ++j)
                vi[ri][j] = ok ? inc[(size_t)n * N_COMM + l + 64 * j] : 0.0f;
#pragma unroll
            for (int j = 0; j < 2; ++j)
                vm[ri][j] = ok ? nm[(size_t)n * DIM_M + l + 64 * j] : 0.0f;
        }
    };
    auto write_chunk = [&](int buf) {
        unsigned short* bi = &T[buf][0];
#pragma unroll
        for (int j = 0; j < 4; ++j) {
            const int cc = l + 64 * j;
            ushort4 p = make_ushort4(f2bf(vi[0][j]), f2bf(vi[1][j]),
                                     f2bf(vi[2][j]), f2bf(vi[3][j]));
            *(ushort4*)&bi[cc * 32 + ((w ^ (cc & 7)) << 2)] = p;
        }
        unsigned short* bm = &T[buf][8192];
#pragma unroll
        for (int j = 0; j < 2; ++j) {
            const int mm = l + 64 * j;
            ushort4 p = make_ushort4(f2bf(vm[0][j]), f2bf(vm[1][j]),
                                     f2bf(vm[2][j]), f2bf(vm[3][j]));
            *(ushort4*)&bm[mm * 32 + ((w ^ (mm & 7)) << 2)] = p;
        }
    };

    f32x4 acc[2][8];
#pragma unroll
    for (int ct = 0; ct < 2; ++ct)
#pragma unroll
        for (int mt = 0; mt < 8; ++mt) acc[ct][mt] = (f32x4){0.f, 0.f, 0.f, 0.f};

    auto compute_chunk = [&](int buf) {
        const unsigned short* bi = &T[buf][0];
        const unsigned short* bm = &T[buf][8192];
        s16x8 a[2];
#pragma unroll
        for (int ct = 0; ct < 2; ++ct) {
            const int cc = (w * 2 + ct) * 16 + lr;
            s16x4 lo = *(const s16x4*)&bi[cc * 32 + (((lk * 2) ^ (cc & 7)) << 2)];
            s16x4 hi = *(const s16x4*)&bi[cc * 32 + (((lk * 2 + 1) ^ (cc & 7)) << 2)];
            a[ct] = __builtin_shufflevector(lo, hi, 0, 1, 2, 3, 4, 5, 6, 7);
        }
#pragma unroll
        for (int mt = 0; mt < 8; ++mt) {
            const int mm = mt * 16 + lr;
            s16x4 lo = *(const s16x4*)&bm[mm * 32 + (((lk * 2) ^ (mm & 7)) << 2)];
            s16x4 hi = *(const s16x4*)&bm[mm * 32 + (((lk * 2 + 1) ^ (mm & 7)) << 2)];
            s16x8 b = __builtin_shufflevector(lo, hi, 0, 1, 2, 3, 4, 5, 6, 7);
            acc[0][mt] = __builtin_amdgcn_mfma_f32_16x16x32_bf16(a[0], b, acc[0][mt], 0, 0, 0);
            acc[1][mt] = __builtin_amdgcn_mfma_f32_16x16x32_bf16(a[1], b, acc[1][mt], 0, 0, 0);
        }
    };

    load_chunk(0);
    write_chunk(0);
    __syncthreads();
    for (int g = 0; g < ng; ++g) {
        if (g + 1 < ng) load_chunk(g + 1);
        compute_chunk(g & 1);
        if (g + 1 < ng) write_chunk((g + 1) & 1);
        __syncthreads();
    }

    float* p = partials + (size_t)bid * (N_COMM * DIM_M);
#pragma unroll
    for (int ct = 0; ct < 2; ++ct)
#pragma unroll
        for (int mt = 0; mt < 8; ++mt)
            *(f32x4*)&p[(size_t)(((ct * 8 + mt) * 512) + tid) * 4] = acc[ct][mt];
}

// ---------- phase 5b: two-stage reduction over permuted partials ----------
__global__ __launch_bounds__(256) void k_comm2a(const float* __restrict__ partials,
                                                float* __restrict__ tmp) {
    const int bid = blockIdx.x;
    const int y = bid >> 5, x = bid & 31;
    const int idx4 = x * 256 + threadIdx.x;
    float4 s = make_float4(0.f, 0.f, 0.f, 0.f);
    for (int ci = 0; ci < CT_NCH / 32; ++ci) {
        float4 v = *(const float4*)&partials[(size_t)(y * (CT_NCH / 32) + ci) * (N_COMM * DIM_M) + idx4 * 4];
        s.x += v.x; s.y += v.y; s.z += v.z; s.w += v.w;
    }
    *(float4*)&tmp[(size_t)y * (N_COMM * DIM_M) + idx4 * 4] = s;
}

__global__ __launch_bounds__(256) void k_comm2b(const float* __restrict__ tmp,
                                                float* __restrict__ out) {
    const int idx4 = blockIdx.x * 256 + threadIdx.x;
    float4 s = make_float4(0.f, 0.f, 0.f, 0.f);
    for (int y = 0; y < 32; ++y) {
        float4 v = *(const float4*)&tmp[(size_t)y * (N_COMM * DIM_M) + idx4 * 4];
        s.x += v.x; s.y += v.y; s.z += v.z; s.w += v.w;
    }
    const int q = idx4 >> 9;
    const int tid = idx4 & 511;
    const int ct = q >> 3, mt = q & 7;
    const int w = tid >> 6, l = tid & 63;
    const int lr = l & 15, lk = l >> 4;
    const int mm = mt * 16 + lr;
    const float sv[4] = {s.x, s.y, s.z, s.w};
#pragma unroll
    for (int reg = 0; reg < 4; ++reg) {
        const int cc = (w * 2 + ct) * 16 + lk * 4 + reg;
        out[(size_t)N_NODES * DIM_M + (size_t)cc * DIM_M + mm] = sv[reg];
    }
}

// ================= FALLBACK PATH (small ws) =================
__global__ __launch_bounds__(256) void k_wconv_old(const float* __restrict__ W_ih,
                                                   const float* __restrict__ W_hh,
                                                   unsigned short* __restrict__ Wt) {
    int idx = blockIdx.x * 256 + threadIdx.x;
    if (idx >= GCOLS * K_TOT) return;
    int col = idx / K_TOT, k = idx % K_TOT;
    float v;
    if (col < 256) {
        v = (k < 448) ? W_ih[(size_t)k * 384 + col]
                      : W_hh[(size_t)(k - 448) * 384 + col];
    } else if (col < 384) {
        v = (k < 448) ? W_ih[(size_t)k * 384 + col] : 0.0f;
    } else {
        v = (k < 448) ? 0.0f : W_hh[(size_t)(k - 448) * 384 + (col - 128)];
    }
    Wt[idx] = f2bf(v);
}

__global__ __launch_bounds__(256) void k_tenc(const unsigned long long* __restrict__ keys,
                                              const unsigned int* __restrict__ cnt,
                                              const int* __restrict__ list,
                                              const int* __restrict__ t,
                                              const int* __restrict__ last_update,
                                              const float* __restrict__ w_time,
                                              const float* __restrict__ b_time,
                                              unsigned short* __restrict__ tenc) {
    int idx = blockIdx.x * 256 + threadIdx.x;
    int r = idx >> 3, slot = idx & 7;
    const unsigned c = *cnt;
    const unsigned cpad = (c + 63u) & ~63u;
    if ((unsigned)r >= cpad) return;
    s16x8 v;
    if ((unsigned)r < c) {
        int node = list[r];
        unsigned long long key = keys[node];
        int ia = (int)(key & 0xffffffffull) - 1;
        int e = (ia < N_EVENTS) ? ia : ia - N_EVENTS;
        float dt = (float)(t[e] - last_update[node]);
#pragma unroll
        for (int j = 0; j < 8; ++j) {
            int cix = slot * 8 + j;
            float arg = __fadd_rn(__fmul_rn(dt, w_time[cix]), b_time[cix]);
            v[j] = (short)f2bf(cosf(arg));
        }
    } else {
#pragma unroll
        for (int j = 0; j < 8; ++j) v[j] = 0;
    }
    *(s16x8*)&tenc[(size_t)r * 64 + slot * 8] = v;
}

__global__ __launch_bounds__(256, 2) void k_gemm_fused(
    const unsigned long long* __restrict__ keys,
    const unsigned int* __restrict__ cnt,
    const int* __restrict__ list,
    const float* __restrict__ event_feat,
    const float* __restrict__ src_embeds,
    const float* __restrict__ dst_embeds,
    const float* __restrict__ mem,
    const unsigned short* __restrict__ tenc,
    const unsigned short* __restrict__ Wt,
    const float* __restrict__ b_ih,
    const float* __restrict__ b_hh,
    float* __restrict__ out) {
    __shared__ unsigned short Xs[2][4][64][8];

    const unsigned c = *cnt;
    const int base = blockIdx.x * 64;
    if ((unsigned)base >= c) return;
    const int tid = threadIdx.x;

    const int srow = tid >> 2;
    const int kslot = tid & 3;
    const int sgrow = base + srow;
    const bool valid = (unsigned)sgrow < c;
    const float *p_es = nullptr, *p_ed = nullptr, *p_ef = nullptr, *p_mem = nullptr;
    const unsigned short* p_te = nullptr;
    if (valid) {
        int node = list[sgrow];
        unsigned long long key = keys[node];
        int ia = (int)(key & 0xffffffffull) - 1;
        int e = (ia < N_EVENTS) ? ia : ia - N_EVENTS;
        const float* sp = src_embeds + (size_t)e * 128;
        const float* dp = dst_embeds + (size_t)e * 128;
        p_es = (ia < N_EVENTS) ? sp : dp;
        p_ed = (ia < N_EVENTS) ? dp : sp;
        p_ef = event_feat + (size_t)e * 128;
        p_te = tenc + (size_t)sgrow * 64;
        p_mem = mem + (size_t)node * 128;
    }

    auto stage = [&](int ch) {
        const int buf = ch & 1;
        const int k0 = ch * 32 + kslot * 8;
        s16x8 v;
        if (valid) {
            if (k0 < 384) {
                const float* p = (k0 < 128) ? (p_es + k0)
                               : (k0 < 256) ? (p_ed + (k0 - 128))
                                            : (p_ef + (k0 - 256));
                float4 a = *(const float4*)p;
                float4 b = *(const float4*)(p + 4);
                v = pack_bf8(a, b);
            } else if (k0 < 448) {
                v = *(const s16x8*)(p_te + (k0 - 384));
            } else {
                const float* p = p_mem + (k0 - 448);
                float4 a = *(const float4*)p;
                float4 b = *(const float4*)(p + 4);
                v = pack_bf8(a, b);
            }
        } else {
#pragma unroll
            for (int j = 0; j < 8; ++j) v[j] = 0;
        }
        *(s16x8*)&Xs[buf][kslot][srow][0] = v;
    };

    const int w = tid >> 6;
    const int l = tid & 63;
    const int lr = l & 15;
    const int lk = l >> 4;

    f32x4 acc[4][8];
#pragma unroll
    for (int rt = 0; rt < 4; ++rt)
#pragma unroll
        for (int i = 0; i < 8; ++i) acc[rt][i] = (f32x4){0.f, 0.f, 0.f, 0.f};

    stage(0);
    __syncthreads();

    for (int ch = 0; ch < 18; ++ch) {
        if (ch < 17) stage(ch + 1);
        const int buf = ch & 1;
        s16x8 a[4];
#pragma unroll
        for (int rt = 0; rt < 4; ++rt)
            a[rt] = *(const s16x8*)&Xs[buf][lk][rt * 16 + lr][0];
#pragma unroll
        for (int i = 0; i < 8; ++i) {
            const int col = (w + 4 * i) * 16 + lr;
            s16x8 b = *(const s16x8*)&Wt[(size_t)col * K_TOT + ch * 32 + lk * 8];
#pragma unroll
            for (int rt = 0; rt < 4; ++rt)
                acc[rt][i] = __builtin_amdgcn_mfma_f32_16x16x32_bf16(
                    a[rt], b, acc[rt][i], 0, 0, 0);
        }
        __syncthreads();
    }

#pragma unroll
    for (int jj = 0; jj < 2; ++jj) {
        const int mcol = (w + 4 * jj) * 16 + lr;
        const float b_r  = b_ih[mcol] + b_hh[mcol];
        const float b_z  = b_ih[128 + mcol] + b_hh[128 + mcol];
        const float b_xn = b_ih[256 + mcol];
        const float b_hn = b_hh[256 + mcol];
#pragma unroll
        for (int rt = 0; rt < 4; ++rt) {
#pragma unroll
            for (int reg = 0; reg < 4; ++reg) {
                const int grow = base + rt * 16 + lk * 4 + reg;
                if ((unsigned)grow < c) {
                    const int node = list[grow];
                    const float h = mem[(size_t)node * 128 + mcol];
                    float rr = sigmoid_f(acc[rt][0 + jj][reg] + b_r);
                    float zz = sigmoid_f(acc[rt][2 + jj][reg] + b_z);
                    float nn = tanh_f(acc[rt][4 + jj][reg] + b_xn +
                                      rr * (acc[rt][6 + jj][reg] + b_hn));
                    out[(size_t)node * 128 + mcol] = (1.0f - zz) * nn + zz * h;
                }
            }
        }
    }
}

__global__ __launch_bounds__(256) void k_comm1(const float* __restrict__ inc,
                                               const float* __restrict__ nm,
                                               float* __restrict__ partials,
                                               int nch, int cpn) {
    __shared__ float inc_s[2][8][128];
    __shared__ float mem_s[2][8][128];

    const int bid = blockIdx.x;
    const int ct2 = bid / nch;
    const int ch  = bid % nch;
    const int n0 = ch * cpn;
    const int n1 = min(N_NODES, n0 + cpn);
    const int tid = threadIdx.x;

    const int srow = tid >> 5;
    const int scol = (tid & 31) * 4;

    auto stage = [&](int g, int buf) {
        const int n = n0 + g * 8 + srow;
        float4 iv = make_float4(0.f, 0.f, 0.f, 0.f);
        float4 mv = make_float4(0.f, 0.f, 0.f, 0.f);
        if (n < n1) {
            iv = *(const float4*)(inc + (size_t)n * N_COMM + ct2 * 128 + scol);
            mv = *(const float4*)(nm + (size_t)n * DIM_M + scol);
        }
        *(float4*)&inc_s[buf][srow][scol] = iv;
        *(float4*)&mem_s[buf][srow][scol] = mv;
    };

    const int c0 = (tid >> 3) * 4;
    const int mb = (tid & 7) * 4;

    float acc[4][4][4];
#pragma unroll
    for (int a = 0; a < 4; ++a)
#pragma unroll
        for (int b = 0; b < 4; ++b)
#pragma unroll
            for (int d = 0; d < 4; ++d) acc[a][b][d] = 0.0f;

    const int ngrp = (n1 - n0 + 7) >> 3;
    stage(0, 0);
    __syncthreads();

    for (int g = 0; g < ngrp; ++g) {
        if (g + 1 < ngrp) stage(g + 1, (g + 1) & 1);
        const int buf = g & 1;
#pragma unroll
        for (int i = 0; i < 8; ++i) {
            const float4 cv = *(const float4*)&inc_s[buf][i][c0];
            const float ca[4] = {cv.x, cv.y, cv.z, cv.w};
#pragma unroll
            for (int j = 0; j < 4; ++j) {
                const float4 mv = *(const float4*)&mem_s[buf][i][j * 32 + mb];
                const float ma[4] = {mv.x, mv.y, mv.z, mv.w};
#pragma unroll
                for (int ci = 0; ci < 4; ++ci)
#pragma unroll
                    for (int mi = 0; mi < 4; ++mi)
                        acc[ci][j][mi] = fmaf(ca[ci], ma[mi], acc[ci][j][mi]);
            }
        }
        __syncthreads();
    }

    float* p = partials + (size_t)bid * (128 * 128);
#pragma unroll
    for (int ci = 0; ci < 4; ++ci)
#pragma unroll
        for (int j = 0; j < 4; ++j)
            *(float4*)(p + (size_t)(c0 + ci) * 128 + j * 32 + mb) =
                make_float4(acc[ci][j][0], acc[ci][j][1], acc[ci][j][2], acc[ci][j][3]);
}

__global__ __launch_bounds__(256) void k_comm2_f(const float* __restrict__ partials,
                                                 float* __restrict__ out,
                                                 int nch) {
    int idx = blockIdx.x * 256 + threadIdx.x;
    if (idx >= N_COMM * DIM_M) return;
    int cg = idx >> 7;
    int m = idx & 127;
    int ct2 = cg >> 7;
    int cl = cg & 127;
    float s = 0.0f;
    for (int ch = 0; ch < nch; ++ch)
        s += partials[((size_t)ct2 * nch + ch) * 16384 + (size_t)cl * 128 + m];
    out[(size_t)N_NODES * DIM_M + idx] = s;
}

extern "C" void kernel_launch(void* const* d_in, const int* in_sizes, int n_in,
                              void* d_out, int out_size, void* d_ws, size_t ws_size,
                              hipStream_t stream) {
    const int* src          = (const int*)d_in[0];
    const int* dst          = (const int*)d_in[1];
    const int* t            = (const int*)d_in[2];
    const int* last_update  = (const int*)d_in[3];
    const float* event_feat = (const float*)d_in[4];
    const float* src_embeds = (const float*)d_in[5];
    const float* dst_embeds = (const float*)d_in[6];
    const float* nodes_mem  = (const float*)d_in[7];
    const float* incidence  = (const float*)d_in[8];
    const float* w_time     = (const float*)d_in[9];
    const float* b_time     = (const float*)d_in[10];
    const float* W_ih       = (const float*)d_in[11];
    const float* W_hh       = (const float*)d_in[12];
    const float* b_ih       = (const float*)d_in[13];
    const float* b_hh       = (const float*)d_in[14];
    float* out = (float*)d_out;

    char* ws = (char*)d_ws;
    unsigned long long* keys = (unsigned long long*)(ws + KEYS_OFF);
    unsigned int* cnt        = (unsigned int*)(ws + CNT_OFF);
    int* list                = (int*)(ws + LIST_OFF);
    int4* einfo              = (int4*)(ws + EINFO_OFF);

    const bool xfit = ws_size >= (size_t)X_OFF + (size_t)X_ROWS * (K_TOT * 2);

    unsigned* bcount = (unsigned*)(ws + (xfit ? BCNT_OFF : BCNT_F_OFF));
    unsigned* boff   = (unsigned*)(ws + (xfit ? BOFF_OFF : BOFF_F_OFF));

    hipMemsetAsync(d_ws, 0, LIST_OFF, stream);  // keys + cnt

    k_agg<<<(2 * N_EVENTS + 255) / 256, 256, 0, stream>>>(src, dst, t, keys);
    k_flag<<<NBLK, 256, 0, stream>>>(src, dst, keys, bcount);
    k_scan<<<1, 512, 0, stream>>>(bcount, boff, cnt);
    k_emit<<<NBLK, 256, 0, stream>>>(src, dst, t, last_update, keys, boff,
                                     list, einfo);

    if (xfit) {
        unsigned short* Wt = (unsigned short*)(ws + WT_OFF);
        unsigned short* X  = (unsigned short*)(ws + X_OFF);
        float* partials    = (float*)(ws + PART_M_OFF);
        float* tmp2        = (float*)(ws + TMP2_OFF);

        k_xbuild<<<XB_GRID + WCONV_BLOCKS + COPY_BLOCKS, 256, 0, stream>>>(
            keys, cnt, einfo, event_feat, src_embeds, dst_embeds,
            nodes_mem, w_time, b_time, W_ih, W_hh, Wt, X, out);
        k_gemm2<<<(X_ROWS / 128) * 2, 512, 0, stream>>>(cnt, list, X, Wt,
                                                        b_ih, b_hh, out);
        k_comm_t<<<CT_NCH, 512, 0, stream>>>(incidence, out, partials);
        k_comm2a<<<1024, 256, 0, stream>>>(partials, tmp2);
        k_comm2b<<<32, 256, 0, stream>>>(tmp2, out);
    } else {
        unsigned short* Wt   = (unsigned short*)(ws + WT_F_OFF);
        unsigned short* tenc = (unsigned short*)(ws + TENC_OFF);
        float* partials      = (float*)(ws + PART_F_OFF);
        int NCH = 512;
        while (NCH > 8 && (size_t)PART_F_OFF + (size_t)NCH * 131072 > ws_size) NCH >>= 1;
        int cpn = (N_NODES + NCH - 1) / NCH;

        k_wconv_old<<<(GCOLS * K_TOT + 255) / 256, 256, 0, stream>>>(W_ih, W_hh, Wt);
        k_tenc<<<(100032 * 8) / 256, 256, 0, stream>>>(keys, cnt, list, t, last_update,
                                                       w_time, b_time, tenc);
        k_gemm_fused<<<100032 / 64, 256, 0, stream>>>(keys, cnt, list, event_feat,
                                                      src_embeds, dst_embeds, nodes_mem,
                                                      tenc, Wt, b_ih, b_hh, out);
        k_copy<<<(N_NODES * 32 + 255) / 256, 256, 0, stream>>>(keys, nodes_mem, out);
        k_comm1<<<2 * NCH, 256, 0, stream>>>(incidence, out, partials, NCH, cpn);
        k_comm2_f<<<(N_COMM * DIM_M + 255) / 256, 256, 0, stream>>>(partials, out, NCH);
    }
}

// Round 20
// 199.367 us; speedup vs baseline: 1.0380x; 1.0380x over previous
//
#include <hip/hip_runtime.h>
#include <hip/hip_bf16.h>
#include <stdint.h>

#define N_NODES   100000
#define N_EVENTS  50000
#define N_COMM    256
#define DIM_M     128
#define K_TOT     576   // 448 msg + 128 mem
#define GCOLS     512
#define INV2PI    0.15915494309189535f
#define XB_GRID   2048
#define WCONV_BLOCKS ((GCOLS * K_TOT + 255) / 256)   // 1152
#define COPY_BLOCKS  512
#define NBLK      ((2 * N_EVENTS + 255) / 256)       // 391

typedef float f32x4 __attribute__((ext_vector_type(4)));
typedef short s16x8 __attribute__((ext_vector_type(8)));
typedef short s16x4 __attribute__((ext_vector_type(4)));

// ---------------- ws layout ----------------
#define KEYS_OFF   0                      // u64[N]
#define CNT_OFF    800000                 // u32
#define LIST_OFF   800008                 // i32[N] -> ends 1200008
#define EINFO_OFF  1200064                // int4[N] = 1.6MB -> ends 2800064
#define WT_OFF     2800128                // bf16 [512][576] -> ends 3389952
#define X_ROWS     100096
#define X_OFF      3390208                // bf16 [100096][576] -> ends 118700800
// comm scratch OVERLAYS X region (X dead before comm runs)
#define PART_M_OFF X_OFF                  // f32 [512][32768] = 67.1MB (permuted)
#define CT_NCH     512
#define CT_CPN     196
#define TMP2_OFF   (PART_M_OFF + 67108864)
// scan scratch overlays TMP2 (scan done long before comm2a writes tmp2)
#define BCNT_OFF   TMP2_OFF
#define BOFF_OFF   (TMP2_OFF + 2048)
// fallback path:
#define WT_F_OFF   1200640
#define TENC_OFF   1790464
#define PART_F_OFF 14594560
#define BCNT_F_OFF PART_F_OFF
#define BOFF_F_OFF (PART_F_OFF + 2048)

__device__ inline unsigned short f2bf(float x) {
    union { float f; unsigned u; } v; v.f = x;
    unsigned r = v.u + 0x7FFFu + ((v.u >> 16) & 1u);
    return (unsigned short)(r >> 16);
}
__device__ inline float bf2f(unsigned short u) {
    union { unsigned u; float f; } v; v.u = ((unsigned)u) << 16;
    return v.f;
}
__device__ inline float cos_rev(float rev) {
    float fr = rev - floorf(rev);
#if __has_builtin(__builtin_amdgcn_cosf)
    return __builtin_amdgcn_cosf(fr);
#else
    return cosf(fr * 6.283185307179586f);
#endif
}
__device__ inline float sigmoid_f(float x) { return 1.0f / (1.0f + __expf(-x)); }
__device__ inline float tanh_f(float x) {
    float t = __expf(2.0f * x);
    return 1.0f - 2.0f / (t + 1.0f);
}
__device__ inline s16x8 pack_bf8(float4 a, float4 b) {
    s16x8 v;
    v[0] = (short)f2bf(a.x); v[1] = (short)f2bf(a.y);
    v[2] = (short)f2bf(a.z); v[3] = (short)f2bf(a.w);
    v[4] = (short)f2bf(b.x); v[5] = (short)f2bf(b.y);
    v[6] = (short)f2bf(b.z); v[7] = (short)f2bf(b.w);
    return v;
}

// ---------- phase 1 ----------
__global__ __launch_bounds__(256) void k_agg(const int* __restrict__ src,
                                             const int* __restrict__ dst,
                                             const int* __restrict__ t,
                                             unsigned long long* __restrict__ keys) {
    int i = blockIdx.x * 256 + threadIdx.x;
    if (i >= 2 * N_EVENTS) return;
    int e = (i < N_EVENTS) ? i : i - N_EVENTS;
    int node = (i < N_EVENTS) ? src[i] : dst[e];
    unsigned long long key =
        ((unsigned long long)(unsigned)t[e] << 32) | (unsigned)(i + 1);
    atomicMax(&keys[node], key);
}

// ---------- phase 2a: flag winners per 256-event block ----------
__global__ __launch_bounds__(256) void k_flag(const int* __restrict__ src,
                                              const int* __restrict__ dst,
                                              const unsigned long long* __restrict__ keys,
                                              unsigned* __restrict__ bcount) {
    const int i = blockIdx.x * 256 + threadIdx.x;
    int win = 0;
    if (i < 2 * N_EVENTS) {
        int e = (i < N_EVENTS) ? i : i - N_EVENTS;
        int node = (i < N_EVENTS) ? src[i] : dst[e];
        win = ((unsigned)(keys[node] & 0xffffffffull) == (unsigned)(i + 1));
    }
    __shared__ unsigned cnt_s;
    if (threadIdx.x == 0) cnt_s = 0;
    __syncthreads();
    unsigned long long m = __ballot(win);
    if ((threadIdx.x & 63) == 0) atomicAdd(&cnt_s, (unsigned)__popcll(m));
    __syncthreads();
    if (threadIdx.x == 0) bcount[blockIdx.x] = cnt_s;
}

// ---------- phase 2b: exclusive scan of block counts (1 block) ----------
__global__ __launch_bounds__(512) void k_scan(const unsigned* __restrict__ bcount,
                                              unsigned* __restrict__ boff,
                                              unsigned int* __restrict__ cnt) {
    __shared__ unsigned s[512];
    const int tid = threadIdx.x;
    unsigned v = (tid < NBLK) ? bcount[tid] : 0;
    s[tid] = v;
    __syncthreads();
    for (int off = 1; off < 512; off <<= 1) {
        unsigned tv = (tid >= off) ? s[tid - off] : 0;
        __syncthreads();
        s[tid] += tv;
        __syncthreads();
    }
    if (tid < NBLK) boff[tid] = s[tid] - v;
    if (tid == NBLK - 1) *cnt = s[tid];
}

// ---------- phase 2c: emit rows in event-block order ----------
__global__ __launch_bounds__(256) void k_emit(const int* __restrict__ src,
                                              const int* __restrict__ dst,
                                              const int* __restrict__ t,
                                              const int* __restrict__ last_update,
                                              const unsigned long long* __restrict__ keys,
                                              const unsigned* __restrict__ boff,
                                              int* __restrict__ list,
                                              int4* __restrict__ einfo) {
    const int i = blockIdx.x * 256 + threadIdx.x;
    __shared__ unsigned lcnt;
    if (threadIdx.x == 0) lcnt = 0;
    __syncthreads();
    if (i < 2 * N_EVENTS) {
        const int e = (i < N_EVENTS) ? i : i - N_EVENTS;
        const int node = (i < N_EVENTS) ? src[i] : dst[e];
        if ((unsigned)(keys[node] & 0xffffffffull) == (unsigned)(i + 1)) {
            unsigned r = atomicAdd(&lcnt, 1u);
            unsigned pos = boff[blockIdx.x] + r;
            list[pos] = node;
            const float dt = (float)(t[e] - last_update[node]);
            einfo[pos] = make_int4(node, i, __float_as_int(dt), 0);
        }
    }
}

// ---------- phase 3a: build X (8 thr/row, 16 gathers in flight) + wconv + copy ----------
__global__ __launch_bounds__(256) void k_xbuild(
    const unsigned long long* __restrict__ keys,
    const unsigned int* __restrict__ cnt,
    const int4* __restrict__ einfo,
    const float* __restrict__ event_feat,
    const float* __restrict__ src_embeds,
    const float* __restrict__ dst_embeds,
    const float* __restrict__ mem,
    const float* __restrict__ w_time,
    const float* __restrict__ b_time,
    const float* __restrict__ W_ih,
    const float* __restrict__ W_hh,
    unsigned short* __restrict__ Wt,
    unsigned short* __restrict__ X,
    float* __restrict__ out) {
    if (blockIdx.x >= XB_GRID + WCONV_BLOCKS) {   // ---- copy-through ----
        const int b = blockIdx.x - (XB_GRID + WCONV_BLOCKS);
        for (int idx = b * 256 + threadIdx.x; idx < N_NODES * 32;
             idx += COPY_BLOCKS * 256) {
            const int n = idx >> 5;
            if (keys[n] == 0ULL)
                ((float4*)out)[idx] = ((const float4*)mem)[idx];
        }
        return;
    }
    if (blockIdx.x >= XB_GRID) {   // ---- fused weight conversion ----
        int idx = (blockIdx.x - XB_GRID) * 256 + threadIdx.x;
        if (idx >= GCOLS * K_TOT) return;
        int col2 = idx / K_TOT, k = idx % K_TOT;
        int mh = col2 >> 8, rem = col2 & 255;
        int g = rem >> 6, m = mh * 64 + (rem & 63);
        float v;
        if (g == 0)      v = (k < 448) ? W_ih[(size_t)k * 384 + m]
                                       : W_hh[(size_t)(k - 448) * 384 + m];
        else if (g == 1) v = (k < 448) ? W_ih[(size_t)k * 384 + 128 + m]
                                       : W_hh[(size_t)(k - 448) * 384 + 128 + m];
        else if (g == 2) v = (k < 448) ? W_ih[(size_t)k * 384 + 256 + m] : 0.0f;
        else             v = (k < 448) ? 0.0f : W_hh[(size_t)(k - 448) * 384 + 256 + m];
        Wt[idx] = f2bf(v);
        return;
    }
    // ---- X build: 8 threads per row, slots s = j*8 + l8, j = 0..8 ----
    const unsigned c = *cnt;
    const unsigned cpad = (c + 127u) & ~127u;
    const int l8 = threadIdx.x & 7;
    const int off = l8 * 8;
    for (unsigned row = (blockIdx.x * 256u + threadIdx.x) >> 3; row < cpad;
         row += (XB_GRID * 256u) >> 3) {
        unsigned short* xp = X + (size_t)row * K_TOT + off;
        if (row >= c) {
            s16x8 z;
#pragma unroll
            for (int q = 0; q < 8; ++q) z[q] = 0;
#pragma unroll
            for (int j = 0; j < 9; ++j) *(s16x8*)(xp + j * 64) = z;
            continue;
        }
        const int4 ei = einfo[row];
        const int ia = ei.y;
        const int e = (ia < N_EVENTS) ? ia : ia - N_EVENTS;
        const float* sp = src_embeds + (size_t)e * 128;
        const float* dp = dst_embeds + (size_t)e * 128;
        const float* pe_s = (ia < N_EVENTS) ? sp : dp;
        const float* pe_d = (ia < N_EVENTS) ? dp : sp;
        const float* pe_f = event_feat + (size_t)e * 128;
        const float* pm   = mem + (size_t)ei.x * 128;
        const float* ps[8] = {pe_s, pe_s + 64, pe_d, pe_d + 64,
                              pe_f, pe_f + 64, pm,   pm + 64};
        float4 d0[8], d1[8];
#pragma unroll
        for (int j = 0; j < 8; ++j) {
            d0[j] = *(const float4*)(ps[j] + off);
            d1[j] = *(const float4*)(ps[j] + off + 4);
        }
        const float dt = __int_as_float(ei.z);
        s16x8 tv;
#pragma unroll
        for (int q = 0; q < 8; ++q) {
            float rev = fmaf(dt, w_time[off + q] * INV2PI, b_time[off + q] * INV2PI);
            tv[q] = (short)f2bf(cos_rev(rev));
        }
#pragma unroll
        for (int j = 0; j < 6; ++j)
            *(s16x8*)(xp + j * 64) = pack_bf8(d0[j], d1[j]);
        *(s16x8*)(xp + 6 * 64) = tv;
        *(s16x8*)(xp + 7 * 64) = pack_bf8(d0[6], d1[6]);
        *(s16x8*)(xp + 8 * 64) = pack_bf8(d0[7], d1[7]);
    }
}

// ---------- phase 3b: MFMA GEMM, BK=32, 3 bufs, counted vmcnt (round-18 exact) ----------
__global__ __launch_bounds__(512, 4) void k_gemm2(
    const unsigned int* __restrict__ cnt,
    const int* __restrict__ list,
    const unsigned short* __restrict__ X,
    const unsigned short* __restrict__ Wt,
    const float* __restrict__ b_ih,
    const float* __restrict__ b_hh,
    float* __restrict__ out) {
    __shared__ unsigned short As[3][128][32];
    __shared__ unsigned short Bs[3][256][32];
    __shared__ int Ls[128];

    const unsigned c = *cnt;
    const int rb = blockIdx.x >> 1;
    const int mh = blockIdx.x & 1;
    const int base = rb * 128;
    if ((unsigned)base >= c) return;
    const int tid = threadIdx.x;
    const int w = tid >> 6, l = tid & 63;
    const int lr = l & 15, lk = l >> 4;
    const int wm = w >> 2, wn = w & 3;

    if (tid < 128)
        Ls[tid] = ((unsigned)(base + tid) < c) ? list[base + tid] : 0;

    const int mcol = mh * 64 + wn * 16 + lr;

    unsigned short hreg[16];
#pragma unroll
    for (int rt = 0; rt < 4; ++rt)
#pragma unroll
        for (int reg = 0; reg < 4; ++reg) {
            const int r = wm * 64 + rt * 16 + lk * 4 + reg;
            hreg[rt * 4 + reg] = X[(size_t)(base + r) * K_TOT + 448 + mcol];
        }

    const int srow = tid >> 2;
    const int sd = tid & 3;
    const int ssl = (sd ^ ((srow >> 1) & 3)) << 3;
    const unsigned short* gA  = X  + (size_t)(base + srow) * K_TOT + ssl;
    const unsigned short* gB0 = Wt + (size_t)(mh * 256 + srow) * K_TOT + ssl;
    const unsigned short* gB1 = Wt + (size_t)(mh * 256 + 128 + srow) * K_TOT + ssl;

#define GLD(SRC, DST) __builtin_amdgcn_global_load_lds( \
        (const __attribute__((address_space(1))) unsigned int*)(SRC), \
        (__attribute__((address_space(3))) unsigned int*)(DST), 16, 0, 0)

    auto stage = [&](int ch, int buf) {
        GLD(gA  + ch * 32, &As[buf][w * 16][0]);
        GLD(gB0 + ch * 32, &Bs[buf][w * 16][0]);
        GLD(gB1 + ch * 32, &Bs[buf][128 + w * 16][0]);
    };

    f32x4 acc[4][4];
#pragma unroll
    for (int rt = 0; rt < 4; ++rt)
#pragma unroll
        for (int i = 0; i < 4; ++i) acc[rt][i] = (f32x4){0.f, 0.f, 0.f, 0.f};

    stage(0, 0);
    stage(1, 1);
    __syncthreads();

#pragma unroll
    for (int ch = 0; ch < 18; ++ch) {
        const int buf = ch % 3;
        if (ch <= 15) stage(ch + 2, (ch + 2) % 3);
        __builtin_amdgcn_s_setprio(1);
        s16x8 a[4];
#pragma unroll
        for (int rt = 0; rt < 4; ++rt) {
            const int r = wm * 64 + rt * 16 + lr;
            const int sl = lk ^ ((r >> 1) & 3);
            a[rt] = *(const s16x8*)&As[buf][r][sl << 3];
        }
#pragma unroll
        for (int i = 0; i < 4; ++i) {
            const int cl = i * 64 + wn * 16 + lr;
            const int slb = lk ^ ((cl >> 1) & 3);
            s16x8 b = *(const s16x8*)&Bs[buf][cl][slb << 3];
#pragma unroll
            for (int rt = 0; rt < 4; ++rt)
                acc[rt][i] = __builtin_amdgcn_mfma_f32_16x16x32_bf16(
                    a[rt], b, acc[rt][i], 0, 0, 0);
        }
        __builtin_amdgcn_s_setprio(0);
        if (ch < 17) {
            __builtin_amdgcn_sched_barrier(0);
            if (ch < 16) asm volatile("s_waitcnt vmcnt(3)" ::: "memory");
            else         asm volatile("s_waitcnt vmcnt(0)" ::: "memory");
            __builtin_amdgcn_s_barrier();
            __builtin_amdgcn_sched_barrier(0);
        }
    }

    const float b_r  = b_ih[mcol] + b_hh[mcol];
    const float b_z  = b_ih[128 + mcol] + b_hh[128 + mcol];
    const float b_xn = b_ih[256 + mcol];
    const float b_hn = b_hh[256 + mcol];
#pragma unroll
    for (int rt = 0; rt < 4; ++rt) {
#pragma unroll
        for (int reg = 0; reg < 4; ++reg) {
            const int r = wm * 64 + rt * 16 + lk * 4 + reg;
            const int grow = base + r;
            if ((unsigned)grow < c) {
                const int node = Ls[r];
                const float h = bf2f(hreg[rt * 4 + reg]);
                float rr = sigmoid_f(acc[rt][0][reg] + b_r);
                float zz = sigmoid_f(acc[rt][1][reg] + b_z);
                float nn = tanh_f(acc[rt][2][reg] + b_xn + rr * (acc[rt][3][reg] + b_hn));
                out[(size_t)node * 128 + mcol] = (1.0f - zz) * nn + zz * h;
            }
        }
    }
#undef GLD
}

// ---------- phase 4 (fallback only): copy-through ----------
__global__ __launch_bounds__(256) void k_copy(const unsigned long long* __restrict__ keys,
                                              const float* __restrict__ nm,
                                              float* __restrict__ out) {
    int idx = blockIdx.x * 256 + threadIdx.x;
    int n = idx >> 5;
    if (n >= N_NODES) return;
    if (keys[n] != 0ULL) return;
    ((float4*)out)[idx] = ((const float4*)nm)[idx];
}

// ---------- phase 5a: comm (round-11 version, unchanged) ----------
__global__ __launch_bounds__(512) void k_comm_t(const float* __restrict__ inc,
                                                const float* __restrict__ nm,
                                                float* __restrict__ partials) {
    __shared__ unsigned short T[2][12288];

    const int bid = blockIdx.x;
    const int n0 = bid * CT_CPN;
    const int n1 = min(N_NODES, n0 + CT_CPN);
    const int ng = (n1 - n0 + 31) >> 5;
    const int tid = threadIdx.x;
    const int w = tid >> 6, l = tid & 63;
    const int lr = l & 15, lk = l >> 4;

    float vi[4][4];
    float vm[4][2];

    auto load_chunk = [&](int g) {
        const int nb = n0 + g * 32 + w * 4;
#pragma unroll
        for (int ri = 0; ri < 4; ++ri) {
            const int n = nb + ri;
            const bool ok = n < n1;
#pragma unroll
            for (int j = 0; j < 4; ++j)
                vi[ri][j] = ok ? inc[(size_t)n * N_COMM + l + 64 * j] : 0.0f;
#pragma unroll
            for (int j = 0; j < 2; ++j)
                vm[ri][j] = ok ? nm[(size_t)n * DIM_M + l + 64 * j] : 0.0f;
        }
    };
    auto write_chunk = [&](int buf) {
        unsigned short* bi = &T[buf][0];
#pragma unroll
        for (int j = 0; j < 4; ++j) {
            const int cc = l + 64 * j;
            ushort4 p = make_ushort4(f2bf(vi[0][j]), f2bf(vi[1][j]),
                                     f2bf(vi[2][j]), f2bf(vi[3][j]));
            *(ushort4*)&bi[cc * 32 + ((w ^ (cc & 7)) << 2)] = p;
        }
        unsigned short* bm = &T[buf][8192];
#pragma unroll
        for (int j = 0; j < 2; ++j) {
            const int mm = l + 64 * j;
            ushort4 p = make_ushort4(f2bf(vm[0][j]), f2bf(vm[1][j]),
                                     f2bf(vm[2][j]), f2bf(vm[3][j]));
            *(ushort4*)&bm[mm * 32 + ((w ^ (mm & 7)) << 2)] = p;
        }
    };

    f32x4 acc[2][8];
#pragma unroll
    for (int ct = 0; ct < 2; ++ct)
#pragma unroll
        for (int mt = 0; mt < 8; ++mt) acc[ct][mt] = (f32x4){0.f, 0.f, 0.f, 0.f};

    auto compute_chunk = [&](int buf) {
        const unsigned short* bi = &T[buf][0];
        const unsigned short* bm = &T[buf][8192];
        s16x8 a[2];
#pragma unroll
        for (int ct = 0; ct < 2; ++ct) {
            const int cc = (w * 2 + ct) * 16 + lr;
            s16x4 lo = *(const s16x4*)&bi[cc * 32 + (((lk * 2) ^ (cc & 7)) << 2)];
            s16x4 hi = *(const s16x4*)&bi[cc * 32 + (((lk * 2 + 1) ^ (cc & 7)) << 2)];
            a[ct] = __builtin_shufflevector(lo, hi, 0, 1, 2, 3, 4, 5, 6, 7);
        }
#pragma unroll
        for (int mt = 0; mt < 8; ++mt) {
            const int mm = mt * 16 + lr;
            s16x4 lo = *(const s16x4*)&bm[mm * 32 + (((lk * 2) ^ (mm & 7)) << 2)];
            s16x4 hi = *(const s16x4*)&bm[mm * 32 + (((lk * 2 + 1) ^ (mm & 7)) << 2)];
            s16x8 b = __builtin_shufflevector(lo, hi, 0, 1, 2, 3, 4, 5, 6, 7);
            acc[0][mt] = __builtin_amdgcn_mfma_f32_16x16x32_bf16(a[0], b, acc[0][mt], 0, 0, 0);
            acc[1][mt] = __builtin_amdgcn_mfma_f32_16x16x32_bf16(a[1], b, acc[1][mt], 0, 0, 0);
        }
    };

    load_chunk(0);
    write_chunk(0);
    __syncthreads();
    for (int g = 0; g < ng; ++g) {
        if (g + 1 < ng) load_chunk(g + 1);
        compute_chunk(g & 1);
        if (g + 1 < ng) write_chunk((g + 1) & 1);
        __syncthreads();
    }

    float* p = partials + (size_t)bid * (N_COMM * DIM_M);
#pragma unroll
    for (int ct = 0; ct < 2; ++ct)
#pragma unroll
        for (int mt = 0; mt < 8; ++mt)
            *(f32x4*)&p[(size_t)(((ct * 8 + mt) * 512) + tid) * 4] = acc[ct][mt];
}

// ---------- phase 5b: two-stage reduction over permuted partials ----------
__global__ __launch_bounds__(256) void k_comm2a(const float* __restrict__ partials,
                                                float* __restrict__ tmp) {
    const int bid = blockIdx.x;
    const int y = bid >> 5, x = bid & 31;
    const int idx4 = x * 256 + threadIdx.x;
    float4 s = make_float4(0.f, 0.f, 0.f, 0.f);
    for (int ci = 0; ci < CT_NCH / 32; ++ci) {
        float4 v = *(const float4*)&partials[(size_t)(y * (CT_NCH / 32) + ci) * (N_COMM * DIM_M) + idx4 * 4];
        s.x += v.x; s.y += v.y; s.z += v.z; s.w += v.w;
    }
    *(float4*)&tmp[(size_t)y * (N_COMM * DIM_M) + idx4 * 4] = s;
}

__global__ __launch_bounds__(256) void k_comm2b(const float* __restrict__ tmp,
                                                float* __restrict__ out) {
    const int idx4 = blockIdx.x * 256 + threadIdx.x;
    float4 s = make_float4(0.f, 0.f, 0.f, 0.f);
    for (int y = 0; y < 32; ++y) {
        float4 v = *(const float4*)&tmp[(size_t)y * (N_COMM * DIM_M) + idx4 * 4];
        s.x += v.x; s.y += v.y; s.z += v.z; s.w += v.w;
    }
    const int q = idx4 >> 9;
    const int tid = idx4 & 511;
    const int ct = q >> 3, mt = q & 7;
    const int w = tid >> 6, l = tid & 63;
    const int lr = l & 15, lk = l >> 4;
    const int mm = mt * 16 + lr;
    const float sv[4] = {s.x, s.y, s.z, s.w};
#pragma unroll
    for (int reg = 0; reg < 4; ++reg) {
        const int cc = (w * 2 + ct) * 16 + lk * 4 + reg;
        out[(size_t)N_NODES * DIM_M + (size_t)cc * DIM_M + mm] = sv[reg];
    }
}

// ================= FALLBACK PATH (small ws) =================
__global__ __launch_bounds__(256) void k_wconv_old(const float* __restrict__ W_ih,
                                                   const float* __restrict__ W_hh,
                                                   unsigned short* __restrict__ Wt) {
    int idx = blockIdx.x * 256 + threadIdx.x;
    if (idx >= GCOLS * K_TOT) return;
    int col = idx / K_TOT, k = idx % K_TOT;
    float v;
    if (col < 256) {
        v = (k < 448) ? W_ih[(size_t)k * 384 + col]
                      : W_hh[(size_t)(k - 448) * 384 + col];
    } else if (col < 384) {
        v = (k < 448) ? W_ih[(size_t)k * 384 + col] : 0.0f;
    } else {
        v = (k < 448) ? 0.0f : W_hh[(size_t)(k - 448) * 384 + (col - 128)];
    }
    Wt[idx] = f2bf(v);
}

__global__ __launch_bounds__(256) void k_tenc(const unsigned long long* __restrict__ keys,
                                              const unsigned int* __restrict__ cnt,
                                              const int* __restrict__ list,
                                              const int* __restrict__ t,
                                              const int* __restrict__ last_update,
                                              const float* __restrict__ w_time,
                                              const float* __restrict__ b_time,
                                              unsigned short* __restrict__ tenc) {
    int idx = blockIdx.x * 256 + threadIdx.x;
    int r = idx >> 3, slot = idx & 7;
    const unsigned c = *cnt;
    const unsigned cpad = (c + 63u) & ~63u;
    if ((unsigned)r >= cpad) return;
    s16x8 v;
    if ((unsigned)r < c) {
        int node = list[r];
        unsigned long long key = keys[node];
        int ia = (int)(key & 0xffffffffull) - 1;
        int e = (ia < N_EVENTS) ? ia : ia - N_EVENTS;
        float dt = (float)(t[e] - last_update[node]);
#pragma unroll
        for (int j = 0; j < 8; ++j) {
            int cix = slot * 8 + j;
            float arg = __fadd_rn(__fmul_rn(dt, w_time[cix]), b_time[cix]);
            v[j] = (short)f2bf(cosf(arg));
        }
    } else {
#pragma unroll
        for (int j = 0; j < 8; ++j) v[j] = 0;
    }
    *(s16x8*)&tenc[(size_t)r * 64 + slot * 8] = v;
}

__global__ __launch_bounds__(256, 2) void k_gemm_fused(
    const unsigned long long* __restrict__ keys,
    const unsigned int* __restrict__ cnt,
    const int* __restrict__ list,
    const float* __restrict__ event_feat,
    const float* __restrict__ src_embeds,
    const float* __restrict__ dst_embeds,
    const float* __restrict__ mem,
    const unsigned short* __restrict__ tenc,
    const unsigned short* __restrict__ Wt,
    const float* __restrict__ b_ih,
    const float* __restrict__ b_hh,
    float* __restrict__ out) {
    __shared__ unsigned short Xs[2][4][64][8];

    const unsigned c = *cnt;
    const int base = blockIdx.x * 64;
    if ((unsigned)base >= c) return;
    const int tid = threadIdx.x;

    const int srow = tid >> 2;
    const int kslot = tid & 3;
    const int sgrow = base + srow;
    const bool valid = (unsigned)sgrow < c;
    const float *p_es = nullptr, *p_ed = nullptr, *p_ef = nullptr, *p_mem = nullptr;
    const unsigned short* p_te = nullptr;
    if (valid) {
        int node = list[sgrow];
        unsigned long long key = keys[node];
        int ia = (int)(key & 0xffffffffull) - 1;
        int e = (ia < N_EVENTS) ? ia : ia - N_EVENTS;
        const float* sp = src_embeds + (size_t)e * 128;
        const float* dp = dst_embeds + (size_t)e * 128;
        p_es = (ia < N_EVENTS) ? sp : dp;
        p_ed = (ia < N_EVENTS) ? dp : sp;
        p_ef = event_feat + (size_t)e * 128;
        p_te = tenc + (size_t)sgrow * 64;
        p_mem = mem + (size_t)node * 128;
    }

    auto stage = [&](int ch) {
        const int buf = ch & 1;
        const int k0 = ch * 32 + kslot * 8;
        s16x8 v;
        if (valid) {
            if (k0 < 384) {
                const float* p = (k0 < 128) ? (p_es + k0)
                               : (k0 < 256) ? (p_ed + (k0 - 128))
                                            : (p_ef + (k0 - 256));
                float4 a = *(const float4*)p;
                float4 b = *(const float4*)(p + 4);
                v = pack_bf8(a, b);
            } else if (k0 < 448) {
                v = *(const s16x8*)(p_te + (k0 - 384));
            } else {
                const float* p = p_mem + (k0 - 448);
                float4 a = *(const float4*)p;
                float4 b = *(const float4*)(p + 4);
                v = pack_bf8(a, b);
            }
        } else {
#pragma unroll
            for (int j = 0; j < 8; ++j) v[j] = 0;
        }
        *(s16x8*)&Xs[buf][kslot][srow][0] = v;
    };

    const int w = tid >> 6;
    const int l = tid & 63;
    const int lr = l & 15;
    const int lk = l >> 4;

    f32x4 acc[4][8];
#pragma unroll
    for (int rt = 0; rt < 4; ++rt)
#pragma unroll
        for (int i = 0; i < 8; ++i) acc[rt][i] = (f32x4){0.f, 0.f, 0.f, 0.f};

    stage(0);
    __syncthreads();

    for (int ch = 0; ch < 18; ++ch) {
        if (ch < 17) stage(ch + 1);
        const int buf = ch & 1;
        s16x8 a[4];
#pragma unroll
        for (int rt = 0; rt < 4; ++rt)
            a[rt] = *(const s16x8*)&Xs[buf][lk][rt * 16 + lr][0];
#pragma unroll
        for (int i = 0; i < 8; ++i) {
            const int col = (w + 4 * i) * 16 + lr;
            s16x8 b = *(const s16x8*)&Wt[(size_t)col * K_TOT + ch * 32 + lk * 8];
#pragma unroll
            for (int rt = 0; rt < 4; ++rt)
                acc[rt][i] = __builtin_amdgcn_mfma_f32_16x16x32_bf16(
                    a[rt], b, acc[rt][i], 0, 0, 0);
        }
        __syncthreads();
    }

#pragma unroll
    for (int jj = 0; jj < 2; ++jj) {
        const int mcol = (w + 4 * jj) * 16 + lr;
        const float b_r  = b_ih[mcol] + b_hh[mcol];
        const float b_z  = b_ih[128 + mcol] + b_hh[128 + mcol];
        const float b_xn = b_ih[256 + mcol];
        const float b_hn = b_hh[256 + mcol];
#pragma unroll
        for (int rt = 0; rt < 4; ++rt) {
#pragma unroll
            for (int reg = 0; reg < 4; ++reg) {
                const int grow = base + rt * 16 + lk * 4 + reg;
                if ((unsigned)grow < c) {
                    const int node = list[grow];
                    const float h = mem[(size_t)node * 128 + mcol];
                    float rr = sigmoid_f(acc[rt][0 + jj][reg] + b_r);
                    float zz = sigmoid_f(acc[rt][2 + jj][reg] + b_z);
                    float nn = tanh_f(acc[rt][4 + jj][reg] + b_xn +
                                      rr * (acc[rt][6 + jj][reg] + b_hn));
                    out[(size_t)node * 128 + mcol] = (1.0f - zz) * nn + zz * h;
                }
            }
        }
    }
}

__global__ __launch_bounds__(256) void k_comm1(const float* __restrict__ inc,
                                               const float* __restrict__ nm,
                                               float* __restrict__ partials,
                                               int nch, int cpn) {
    __shared__ float inc_s[2][8][128];
    __shared__ float mem_s[2][8][128];

    const int bid = blockIdx.x;
    const int ct2 = bid / nch;
    const int ch  = bid % nch;
    const int n0 = ch * cpn;
    const int n1 = min(N_NODES, n0 + cpn);
    const int tid = threadIdx.x;

    const int srow = tid >> 5;
    const int scol = (tid & 31) * 4;

    auto stage = [&](int g, int buf) {
        const int n = n0 + g * 8 + srow;
        float4 iv = make_float4(0.f, 0.f, 0.f, 0.f);
        float4 mv = make_float4(0.f, 0.f, 0.f, 0.f);
        if (n < n1) {
            iv = *(const float4*)(inc + (size_t)n * N_COMM + ct2 * 128 + scol);
            mv = *(const float4*)(nm + (size_t)n * DIM_M + scol);
        }
        *(float4*)&inc_s[buf][srow][scol] = iv;
        *(float4*)&mem_s[buf][srow][scol] = mv;
    };

    const int c0 = (tid >> 3) * 4;
    const int mb = (tid & 7) * 4;

    float acc[4][4][4];
#pragma unroll
    for (int a = 0; a < 4; ++a)
#pragma unroll
        for (int b = 0; b < 4; ++b)
#pragma unroll
            for (int d = 0; d < 4; ++d) acc[a][b][d] = 0.0f;

    const int ngrp = (n1 - n0 + 7) >> 3;
    stage(0, 0);
    __syncthreads();

    for (int g = 0; g < ngrp; ++g) {
        if (g + 1 < ngrp) stage(g + 1, (g + 1) & 1);
        const int buf = g & 1;
#pragma unroll
        for (int i = 0; i < 8; ++i) {
            const float4 cv = *(const float4*)&inc_s[buf][i][c0];
            const float ca[4] = {cv.x, cv.y, cv.z, cv.w};
#pragma unroll
            for (int j = 0; j < 4; ++j) {
                const float4 mv = *(const float4*)&mem_s[buf][i][j * 32 + mb];
                const float ma[4] = {mv.x, mv.y, mv.z, mv.w};
#pragma unroll
                for (int ci = 0; ci < 4; ++ci)
#pragma unroll
                    for (int mi = 0; mi < 4; ++mi)
                        acc[ci][j][mi] = fmaf(ca[ci], ma[mi], acc[ci][j][mi]);
            }
        }
        __syncthreads();
    }

    float* p = partials + (size_t)bid * (128 * 128);
#pragma unroll
    for (int ci = 0; ci < 4; ++ci)
#pragma unroll
        for (int j = 0; j < 4; ++j)
            *(float4*)(p + (size_t)(c0 + ci) * 128 + j * 32 + mb) =
                make_float4(acc[ci][j][0], acc[ci][j][1], acc[ci][j][2], acc[ci][j][3]);
}

__global__ __launch_bounds__(256) void k_comm2_f(const float* __restrict__ partials,
                                                 float* __restrict__ out,
                                                 int nch) {
    int idx = blockIdx.x * 256 + threadIdx.x;
    if (idx >= N_COMM * DIM_M) return;
    int cg = idx >> 7;
    int m = idx & 127;
    int ct2 = cg >> 7;
    int cl = cg & 127;
    float s = 0.0f;
    for (int ch = 0; ch < nch; ++ch)
        s += partials[((size_t)ct2 * nch + ch) * 16384 + (size_t)cl * 128 + m];
    out[(size_t)N_NODES * DIM_M + idx] = s;
}

extern "C" void kernel_launch(void* const* d_in, const int* in_sizes, int n_in,
                              void* d_out, int out_size, void* d_ws, size_t ws_size,
                              hipStream_t stream) {
    const int* src          = (const int*)d_in[0];
    const int* dst          = (const int*)d_in[1];
    const int* t            = (const int*)d_in[2];
    const int* last_update  = (const int*)d_in[3];
    const float* event_feat = (const float*)d_in[4];
    const float* src_embeds = (const float*)d_in[5];
    const float* dst_embeds = (const float*)d_in[6];
    const float* nodes_mem  = (const float*)d_in[7];
    const float* incidence  = (const float*)d_in[8];
    const float* w_time     = (const float*)d_in[9];
    const float* b_time     = (const float*)d_in[10];
    const float* W_ih       = (const float*)d_in[11];
    const float* W_hh       = (const float*)d_in[12];
    const float* b_ih       = (const float*)d_in[13];
    const float* b_hh       = (const float*)d_in[14];
    float* out = (float*)d_out;

    char* ws = (char*)d_ws;
    unsigned long long* keys = (unsigned long long*)(ws + KEYS_OFF);
    unsigned int* cnt        = (unsigned int*)(ws + CNT_OFF);
    int* list                = (int*)(ws + LIST_OFF);
    int4* einfo              = (int4*)(ws + EINFO_OFF);

    const bool xfit = ws_size >= (size_t)X_OFF + (size_t)X_ROWS * (K_TOT * 2);

    unsigned* bcount = (unsigned*)(ws + (xfit ? BCNT_OFF : BCNT_F_OFF));
    unsigned* boff   = (unsigned*)(ws + (xfit ? BOFF_OFF : BOFF_F_OFF));

    hipMemsetAsync(d_ws, 0, LIST_OFF, stream);  // keys + cnt

    k_agg<<<(2 * N_EVENTS + 255) / 256, 256, 0, stream>>>(src, dst, t, keys);
    k_flag<<<NBLK, 256, 0, stream>>>(src, dst, keys, bcount);
    k_scan<<<1, 512, 0, stream>>>(bcount, boff, cnt);
    k_emit<<<NBLK, 256, 0, stream>>>(src, dst, t, last_update, keys, boff,
                                     list, einfo);

    if (xfit) {
        unsigned short* Wt = (unsigned short*)(ws + WT_OFF);
        unsigned short* X  = (unsigned short*)(ws + X_OFF);
        float* partials    = (float*)(ws + PART_M_OFF);
        float* tmp2        = (float*)(ws + TMP2_OFF);

        k_xbuild<<<XB_GRID + WCONV_BLOCKS + COPY_BLOCKS, 256, 0, stream>>>(
            keys, cnt, einfo, event_feat, src_embeds, dst_embeds,
            nodes_mem, w_time, b_time, W_ih, W_hh, Wt, X, out);
        k_gemm2<<<(X_ROWS / 128) * 2, 512, 0, stream>>>(cnt, list, X, Wt,
                                                        b_ih, b_hh, out);
        k_comm_t<<<CT_NCH, 512, 0, stream>>>(incidence, out, partials);
        k_comm2a<<<1024, 256, 0, stream>>>(partials, tmp2);
        k_comm2b<<<32, 256, 0, stream>>>(tmp2, out);
    } else {
        unsigned short* Wt   = (unsigned short*)(ws + WT_F_OFF);
        unsigned short* tenc = (unsigned short*)(ws + TENC_OFF);
        float* partials      = (float*)(ws + PART_F_OFF);
        int NCH = 512;
        while (NCH > 8 && (size_t)PART_F_OFF + (size_t)NCH * 131072 > ws_size) NCH >>= 1;
        int cpn = (N_NODES + NCH - 1) / NCH;

        k_wconv_old<<<(GCOLS * K_TOT + 255) / 256, 256, 0, stream>>>(W_ih, W_hh, Wt);
        k_tenc<<<(100032 * 8) / 256, 256, 0, stream>>>(keys, cnt, list, t, last_update,
                                                       w_time, b_time, tenc);
        k_gemm_fused<<<100032 / 64, 256, 0, stream>>>(keys, cnt, list, event_feat,
                                                      src_embeds, dst_embeds, nodes_mem,
                                                      tenc, Wt, b_ih, b_hh, out);
        k_copy<<<(N_NODES * 32 + 255) / 256, 256, 0, stream>>>(keys, nodes_mem, out);
        k_comm1<<<2 * NCH, 256, 0, stream>>>(incidence, out, partials, NCH, cpn);
        k_comm2_f<<<(N_COMM * DIM_M + 255) / 256, 256, 0, stream>>>(partials, out, NCH);
    }
}

// Round 21
// 198.897 us; speedup vs baseline: 1.0404x; 1.0024x over previous
//
#include <hip/hip_runtime.h>
#include <hip/hip_bf16.h>
#include <stdint.h>

#define N_NODES   100000
#define N_EVENTS  50000
#define N_COMM    256
#define DIM_M     128
#define K_TOT     576   // 448 msg + 128 mem
#define GCOLS     512
#define INV2PI    0.15915494309189535f
#define XB_GRID   2048
#define WCONV_BLOCKS ((GCOLS * K_TOT + 255) / 256)   // 1152
#define COPY_BLOCKS  512
#define NBLK      ((2 * N_EVENTS + 255) / 256)       // 391

typedef float f32x4 __attribute__((ext_vector_type(4)));
typedef short s16x8 __attribute__((ext_vector_type(8)));
typedef short s16x4 __attribute__((ext_vector_type(4)));

// ---------------- ws layout ----------------
#define KEYS_OFF   0                      // u64[N]
#define CNT_OFF    800000                 // u32
#define LIST_OFF   800008                 // i32[N] -> ends 1200008
#define EINFO_OFF  1200064                // int4[N] = 1.6MB -> ends 2800064
#define WT_OFF     2800128                // bf16 [512][576] -> ends 3389952
#define X_ROWS     100096
#define X_OFF      3390208                // bf16 [100096][576] -> ends 118700800
// comm scratch OVERLAYS X region (X dead before comm runs)
#define PART_M_OFF X_OFF                  // f32 [512][32768] = 67.1MB (permuted)
#define CT_NCH     512
#define CT_CPN     196
#define TMP2_OFF   (PART_M_OFF + 67108864)
// scan scratch overlays TMP2 (scan done long before comm2a writes tmp2)
#define BCNT_OFF   TMP2_OFF
#define BOFF_OFF   (TMP2_OFF + 2048)
// fallback path:
#define WT_F_OFF   1200640
#define TENC_OFF   1790464
#define PART_F_OFF 14594560
#define BCNT_F_OFF PART_F_OFF
#define BOFF_F_OFF (PART_F_OFF + 2048)

__device__ inline unsigned short f2bf(float x) {
    union { float f; unsigned u; } v; v.f = x;
    unsigned r = v.u + 0x7FFFu + ((v.u >> 16) & 1u);
    return (unsigned short)(r >> 16);
}
__device__ inline float bf2f(unsigned short u) {
    union { unsigned u; float f; } v; v.u = ((unsigned)u) << 16;
    return v.f;
}
__device__ inline float cos_rev(float rev) {
    float fr = rev - floorf(rev);
#if __has_builtin(__builtin_amdgcn_cosf)
    return __builtin_amdgcn_cosf(fr);
#else
    return cosf(fr * 6.283185307179586f);
#endif
}
__device__ inline float sigmoid_f(float x) { return 1.0f / (1.0f + __expf(-x)); }
__device__ inline float tanh_f(float x) {
    float t = __expf(2.0f * x);
    return 1.0f - 2.0f / (t + 1.0f);
}
__device__ inline s16x8 pack_bf8(float4 a, float4 b) {
    s16x8 v;
    v[0] = (short)f2bf(a.x); v[1] = (short)f2bf(a.y);
    v[2] = (short)f2bf(a.z); v[3] = (short)f2bf(a.w);
    v[4] = (short)f2bf(b.x); v[5] = (short)f2bf(b.y);
    v[6] = (short)f2bf(b.z); v[7] = (short)f2bf(b.w);
    return v;
}

// ---------- phase 1 ----------
__global__ __launch_bounds__(256) void k_agg(const int* __restrict__ src,
                                             const int* __restrict__ dst,
                                             const int* __restrict__ t,
                                             unsigned long long* __restrict__ keys) {
    int i = blockIdx.x * 256 + threadIdx.x;
    if (i >= 2 * N_EVENTS) return;
    int e = (i < N_EVENTS) ? i : i - N_EVENTS;
    int node = (i < N_EVENTS) ? src[i] : dst[e];
    unsigned long long key =
        ((unsigned long long)(unsigned)t[e] << 32) | (unsigned)(i + 1);
    atomicMax(&keys[node], key);
}

// ---------- phase 2a: flag winners per 256-event block ----------
__global__ __launch_bounds__(256) void k_flag(const int* __restrict__ src,
                                              const int* __restrict__ dst,
                                              const unsigned long long* __restrict__ keys,
                                              unsigned* __restrict__ bcount) {
    const int i = blockIdx.x * 256 + threadIdx.x;
    int win = 0;
    if (i < 2 * N_EVENTS) {
        int e = (i < N_EVENTS) ? i : i - N_EVENTS;
        int node = (i < N_EVENTS) ? src[i] : dst[e];
        win = ((unsigned)(keys[node] & 0xffffffffull) == (unsigned)(i + 1));
    }
    __shared__ unsigned cnt_s;
    if (threadIdx.x == 0) cnt_s = 0;
    __syncthreads();
    unsigned long long m = __ballot(win);
    if ((threadIdx.x & 63) == 0) atomicAdd(&cnt_s, (unsigned)__popcll(m));
    __syncthreads();
    if (threadIdx.x == 0) bcount[blockIdx.x] = cnt_s;
}

// ---------- phase 2b: exclusive scan of block counts (1 block) ----------
__global__ __launch_bounds__(512) void k_scan(const unsigned* __restrict__ bcount,
                                              unsigned* __restrict__ boff,
                                              unsigned int* __restrict__ cnt) {
    __shared__ unsigned s[512];
    const int tid = threadIdx.x;
    unsigned v = (tid < NBLK) ? bcount[tid] : 0;
    s[tid] = v;
    __syncthreads();
    for (int off = 1; off < 512; off <<= 1) {
        unsigned tv = (tid >= off) ? s[tid - off] : 0;
        __syncthreads();
        s[tid] += tv;
        __syncthreads();
    }
    if (tid < NBLK) boff[tid] = s[tid] - v;
    if (tid == NBLK - 1) *cnt = s[tid];
}

// ---------- phase 2c: emit rows in event-block order ----------
__global__ __launch_bounds__(256) void k_emit(const int* __restrict__ src,
                                              const int* __restrict__ dst,
                                              const int* __restrict__ t,
                                              const int* __restrict__ last_update,
                                              const unsigned long long* __restrict__ keys,
                                              const unsigned* __restrict__ boff,
                                              int* __restrict__ list,
                                              int4* __restrict__ einfo) {
    const int i = blockIdx.x * 256 + threadIdx.x;
    __shared__ unsigned lcnt;
    if (threadIdx.x == 0) lcnt = 0;
    __syncthreads();
    if (i < 2 * N_EVENTS) {
        const int e = (i < N_EVENTS) ? i : i - N_EVENTS;
        const int node = (i < N_EVENTS) ? src[i] : dst[e];
        if ((unsigned)(keys[node] & 0xffffffffull) == (unsigned)(i + 1)) {
            unsigned r = atomicAdd(&lcnt, 1u);
            unsigned pos = boff[blockIdx.x] + r;
            list[pos] = node;
            const float dt = (float)(t[e] - last_update[node]);
            einfo[pos] = make_int4(node, i, __float_as_int(dt), 0);
        }
    }
}

// ---------- phase 3a: build X (8 thr/row, 16 gathers in flight) + wconv + copy ----------
__global__ __launch_bounds__(256) void k_xbuild(
    const unsigned long long* __restrict__ keys,
    const unsigned int* __restrict__ cnt,
    const int4* __restrict__ einfo,
    const float* __restrict__ event_feat,
    const float* __restrict__ src_embeds,
    const float* __restrict__ dst_embeds,
    const float* __restrict__ mem,
    const float* __restrict__ w_time,
    const float* __restrict__ b_time,
    const float* __restrict__ W_ih,
    const float* __restrict__ W_hh,
    unsigned short* __restrict__ Wt,
    unsigned short* __restrict__ X,
    float* __restrict__ out) {
    if (blockIdx.x >= XB_GRID + WCONV_BLOCKS) {   // ---- copy-through ----
        const int b = blockIdx.x - (XB_GRID + WCONV_BLOCKS);
        for (int idx = b * 256 + threadIdx.x; idx < N_NODES * 32;
             idx += COPY_BLOCKS * 256) {
            const int n = idx >> 5;
            if (keys[n] == 0ULL)
                ((float4*)out)[idx] = ((const float4*)mem)[idx];
        }
        return;
    }
    if (blockIdx.x >= XB_GRID) {   // ---- fused weight conversion ----
        int idx = (blockIdx.x - XB_GRID) * 256 + threadIdx.x;
        if (idx >= GCOLS * K_TOT) return;
        int col2 = idx / K_TOT, k = idx % K_TOT;
        int mh = col2 >> 8, rem = col2 & 255;
        int g = rem >> 6, m = mh * 64 + (rem & 63);
        float v;
        if (g == 0)      v = (k < 448) ? W_ih[(size_t)k * 384 + m]
                                       : W_hh[(size_t)(k - 448) * 384 + m];
        else if (g == 1) v = (k < 448) ? W_ih[(size_t)k * 384 + 128 + m]
                                       : W_hh[(size_t)(k - 448) * 384 + 128 + m];
        else if (g == 2) v = (k < 448) ? W_ih[(size_t)k * 384 + 256 + m] : 0.0f;
        else             v = (k < 448) ? 0.0f : W_hh[(size_t)(k - 448) * 384 + 256 + m];
        Wt[idx] = f2bf(v);
        return;
    }
    // ---- X build: 8 threads per row, slots s = j*8 + l8, j = 0..8 ----
    const unsigned c = *cnt;
    const unsigned cpad = (c + 127u) & ~127u;
    const int l8 = threadIdx.x & 7;
    const int off = l8 * 8;
    for (unsigned row = (blockIdx.x * 256u + threadIdx.x) >> 3; row < cpad;
         row += (XB_GRID * 256u) >> 3) {
        unsigned short* xp = X + (size_t)row * K_TOT + off;
        if (row >= c) {
            s16x8 z;
#pragma unroll
            for (int q = 0; q < 8; ++q) z[q] = 0;
#pragma unroll
            for (int j = 0; j < 9; ++j) *(s16x8*)(xp + j * 64) = z;
            continue;
        }
        const int4 ei = einfo[row];
        const int ia = ei.y;
        const int e = (ia < N_EVENTS) ? ia : ia - N_EVENTS;
        const float* sp = src_embeds + (size_t)e * 128;
        const float* dp = dst_embeds + (size_t)e * 128;
        const float* pe_s = (ia < N_EVENTS) ? sp : dp;
        const float* pe_d = (ia < N_EVENTS) ? dp : sp;
        const float* pe_f = event_feat + (size_t)e * 128;
        const float* pm   = mem + (size_t)ei.x * 128;
        const float* ps[8] = {pe_s, pe_s + 64, pe_d, pe_d + 64,
                              pe_f, pe_f + 64, pm,   pm + 64};
        float4 d0[8], d1[8];
#pragma unroll
        for (int j = 0; j < 8; ++j) {
            d0[j] = *(const float4*)(ps[j] + off);
            d1[j] = *(const float4*)(ps[j] + off + 4);
        }
        const float dt = __int_as_float(ei.z);
        s16x8 tv;
#pragma unroll
        for (int q = 0; q < 8; ++q) {
            float rev = fmaf(dt, w_time[off + q] * INV2PI, b_time[off + q] * INV2PI);
            tv[q] = (short)f2bf(cos_rev(rev));
        }
#pragma unroll
        for (int j = 0; j < 6; ++j)
            *(s16x8*)(xp + j * 64) = pack_bf8(d0[j], d1[j]);
        *(s16x8*)(xp + 6 * 64) = tv;
        *(s16x8*)(xp + 7 * 64) = pack_bf8(d0[6], d1[6]);
        *(s16x8*)(xp + 8 * 64) = pack_bf8(d0[7], d1[7]);
    }
}

// ---------- phase 3b: MFMA GEMM, BK=32, 3 bufs, counted vmcnt (round-18 exact) ----------
__global__ __launch_bounds__(512, 4) void k_gemm2(
    const unsigned int* __restrict__ cnt,
    const int* __restrict__ list,
    const unsigned short* __restrict__ X,
    const unsigned short* __restrict__ Wt,
    const float* __restrict__ b_ih,
    const float* __restrict__ b_hh,
    float* __restrict__ out) {
    __shared__ unsigned short As[3][128][32];
    __shared__ unsigned short Bs[3][256][32];
    __shared__ int Ls[128];

    const unsigned c = *cnt;
    const int rb = blockIdx.x >> 1;
    const int mh = blockIdx.x & 1;
    const int base = rb * 128;
    if ((unsigned)base >= c) return;
    const int tid = threadIdx.x;
    const int w = tid >> 6, l = tid & 63;
    const int lr = l & 15, lk = l >> 4;
    const int wm = w >> 2, wn = w & 3;

    if (tid < 128)
        Ls[tid] = ((unsigned)(base + tid) < c) ? list[base + tid] : 0;

    const int mcol = mh * 64 + wn * 16 + lr;

    unsigned short hreg[16];
#pragma unroll
    for (int rt = 0; rt < 4; ++rt)
#pragma unroll
        for (int reg = 0; reg < 4; ++reg) {
            const int r = wm * 64 + rt * 16 + lk * 4 + reg;
            hreg[rt * 4 + reg] = X[(size_t)(base + r) * K_TOT + 448 + mcol];
        }

    const int srow = tid >> 2;
    const int sd = tid & 3;
    const int ssl = (sd ^ ((srow >> 1) & 3)) << 3;
    const unsigned short* gA  = X  + (size_t)(base + srow) * K_TOT + ssl;
    const unsigned short* gB0 = Wt + (size_t)(mh * 256 + srow) * K_TOT + ssl;
    const unsigned short* gB1 = Wt + (size_t)(mh * 256 + 128 + srow) * K_TOT + ssl;

#define GLD(SRC, DST) __builtin_amdgcn_global_load_lds( \
        (const __attribute__((address_space(1))) unsigned int*)(SRC), \
        (__attribute__((address_space(3))) unsigned int*)(DST), 16, 0, 0)

    auto stage = [&](int ch, int buf) {
        GLD(gA  + ch * 32, &As[buf][w * 16][0]);
        GLD(gB0 + ch * 32, &Bs[buf][w * 16][0]);
        GLD(gB1 + ch * 32, &Bs[buf][128 + w * 16][0]);
    };

    f32x4 acc[4][4];
#pragma unroll
    for (int rt = 0; rt < 4; ++rt)
#pragma unroll
        for (int i = 0; i < 4; ++i) acc[rt][i] = (f32x4){0.f, 0.f, 0.f, 0.f};

    stage(0, 0);
    stage(1, 1);
    __syncthreads();

#pragma unroll
    for (int ch = 0; ch < 18; ++ch) {
        const int buf = ch % 3;
        if (ch <= 15) stage(ch + 2, (ch + 2) % 3);
        __builtin_amdgcn_s_setprio(1);
        s16x8 a[4];
#pragma unroll
        for (int rt = 0; rt < 4; ++rt) {
            const int r = wm * 64 + rt * 16 + lr;
            const int sl = lk ^ ((r >> 1) & 3);
            a[rt] = *(const s16x8*)&As[buf][r][sl << 3];
        }
#pragma unroll
        for (int i = 0; i < 4; ++i) {
            const int cl = i * 64 + wn * 16 + lr;
            const int slb = lk ^ ((cl >> 1) & 3);
            s16x8 b = *(const s16x8*)&Bs[buf][cl][slb << 3];
#pragma unroll
            for (int rt = 0; rt < 4; ++rt)
                acc[rt][i] = __builtin_amdgcn_mfma_f32_16x16x32_bf16(
                    a[rt], b, acc[rt][i], 0, 0, 0);
        }
        __builtin_amdgcn_s_setprio(0);
        if (ch < 17) {
            __builtin_amdgcn_sched_barrier(0);
            if (ch < 16) asm volatile("s_waitcnt vmcnt(3)" ::: "memory");
            else         asm volatile("s_waitcnt vmcnt(0)" ::: "memory");
            __builtin_amdgcn_s_barrier();
            __builtin_amdgcn_sched_barrier(0);
        }
    }

    const float b_r  = b_ih[mcol] + b_hh[mcol];
    const float b_z  = b_ih[128 + mcol] + b_hh[128 + mcol];
    const float b_xn = b_ih[256 + mcol];
    const float b_hn = b_hh[256 + mcol];
#pragma unroll
    for (int rt = 0; rt < 4; ++rt) {
#pragma unroll
        for (int reg = 0; reg < 4; ++reg) {
            const int r = wm * 64 + rt * 16 + lk * 4 + reg;
            const int grow = base + r;
            if ((unsigned)grow < c) {
                const int node = Ls[r];
                const float h = bf2f(hreg[rt * 4 + reg]);
                float rr = sigmoid_f(acc[rt][0][reg] + b_r);
                float zz = sigmoid_f(acc[rt][1][reg] + b_z);
                float nn = tanh_f(acc[rt][2][reg] + b_xn + rr * (acc[rt][3][reg] + b_hn));
                out[(size_t)node * 128 + mcol] = (1.0f - zz) * nn + zz * h;
            }
        }
    }
#undef GLD
}

// ---------- phase 4 (fallback only): copy-through ----------
__global__ __launch_bounds__(256) void k_copy(const unsigned long long* __restrict__ keys,
                                              const float* __restrict__ nm,
                                              float* __restrict__ out) {
    int idx = blockIdx.x * 256 + threadIdx.x;
    int n = idx >> 5;
    if (n >= N_NODES) return;
    if (keys[n] != 0ULL) return;
    ((float4*)out)[idx] = ((const float4*)nm)[idx];
}

// ---------- phase 5a: comm (round-11 version, unchanged) ----------
__global__ __launch_bounds__(512) void k_comm_t(const float* __restrict__ inc,
                                                const float* __restrict__ nm,
                                                float* __restrict__ partials) {
    __shared__ unsigned short T[2][12288];

    const int bid = blockIdx.x;
    const int n0 = bid * CT_CPN;
    const int n1 = min(N_NODES, n0 + CT_CPN);
    const int ng = (n1 - n0 + 31) >> 5;
    const int tid = threadIdx.x;
    const int w = tid >> 6, l = tid & 63;
    const int lr = l & 15, lk = l >> 4;

    float vi[4][4];
    float vm[4][2];

    auto load_chunk = [&](int g) {
        const int nb = n0 + g * 32 + w * 4;
#pragma unroll
        for (int ri = 0; ri < 4; ++ri) {
            const int n = nb + ri;
            const bool ok = n < n1;
#pragma unroll
            for (int j = 0; j < 4; ++j)
                vi[ri][j] = ok ? inc[(size_t)n * N_COMM + l + 64 * j] : 0.0f;
#pragma unroll
            for (int j = 0; j < 2; ++j)
                vm[ri][j] = ok ? nm[(size_t)n * DIM_M + l + 64 * j] : 0.0f;
        }
    };
    auto write_chunk = [&](int buf) {
        unsigned short* bi = &T[buf][0];
#pragma unroll
        for (int j = 0; j < 4; ++j) {
            const int cc = l + 64 * j;
            ushort4 p = make_ushort4(f2bf(vi[0][j]), f2bf(vi[1][j]),
                                     f2bf(vi[2][j]), f2bf(vi[3][j]));
            *(ushort4*)&bi[cc * 32 + ((w ^ (cc & 7)) << 2)] = p;
        }
        unsigned short* bm = &T[buf][8192];
#pragma unroll
        for (int j = 0; j < 2; ++j) {
            const int mm = l + 64 * j;
            ushort4 p = make_ushort4(f2bf(vm[0][j]), f2bf(vm[1][j]),
                                     f2bf(vm[2][j]), f2bf(vm[3][j]));
            *(ushort4*)&bm[mm * 32 + ((w ^ (mm & 7)) << 2)] = p;
        }
    };

    f32x4 acc[2][8];
#pragma unroll
    for (int ct = 0; ct < 2; ++ct)
#pragma unroll
        for (int mt = 0; mt < 8; ++mt) acc[ct][mt] = (f32x4){0.f, 0.f, 0.f, 0.f};

    auto compute_chunk = [&](int buf) {
        const unsigned short* bi = &T[buf][0];
        const unsigned short* bm = &T[buf][8192];
        s16x8 a[2];
#pragma unroll
        for (int ct = 0; ct < 2; ++ct) {
            const int cc = (w * 2 + ct) * 16 + lr;
            s16x4 lo = *(const s16x4*)&bi[cc * 32 + (((lk * 2) ^ (cc & 7)) << 2)];
            s16x4 hi = *(const s16x4*)&bi[cc * 32 + (((lk * 2 + 1) ^ (cc & 7)) << 2)];
            a[ct] = __builtin_shufflevector(lo, hi, 0, 1, 2, 3, 4, 5, 6, 7);
        }
#pragma unroll
        for (int mt = 0; mt < 8; ++mt) {
            const int mm = mt * 16 + lr;
            s16x4 lo = *(const s16x4*)&bm[mm * 32 + (((lk * 2) ^ (mm & 7)) << 2)];
            s16x4 hi = *(const s16x4*)&bm[mm * 32 + (((lk * 2 + 1) ^ (mm & 7)) << 2)];
            s16x8 b = __builtin_shufflevector(lo, hi, 0, 1, 2, 3, 4, 5, 6, 7);
            acc[0][mt] = __builtin_amdgcn_mfma_f32_16x16x32_bf16(a[0], b, acc[0][mt], 0, 0, 0);
            acc[1][mt] = __builtin_amdgcn_mfma_f32_16x16x32_bf16(a[1], b, acc[1][mt], 0, 0, 0);
        }
    };

    load_chunk(0);
    write_chunk(0);
    __syncthreads();
    for (int g = 0; g < ng; ++g) {
        if (g + 1 < ng) load_chunk(g + 1);
        compute_chunk(g & 1);
        if (g + 1 < ng) write_chunk((g + 1) & 1);
        __syncthreads();
    }

    float* p = partials + (size_t)bid * (N_COMM * DIM_M);
#pragma unroll
    for (int ct = 0; ct < 2; ++ct)
#pragma unroll
        for (int mt = 0; mt < 8; ++mt)
            *(f32x4*)&p[(size_t)(((ct * 8 + mt) * 512) + tid) * 4] = acc[ct][mt];
}

// ---------- phase 5b: two-stage reduction over permuted partials ----------
__global__ __launch_bounds__(256) void k_comm2a(const float* __restrict__ partials,
                                                float* __restrict__ tmp) {
    const int bid = blockIdx.x;
    const int y = bid >> 5, x = bid & 31;
    const int idx4 = x * 256 + threadIdx.x;
    float4 s = make_float4(0.f, 0.f, 0.f, 0.f);
    for (int ci = 0; ci < CT_NCH / 32; ++ci) {
        float4 v = *(const float4*)&partials[(size_t)(y * (CT_NCH / 32) + ci) * (N_COMM * DIM_M) + idx4 * 4];
        s.x += v.x; s.y += v.y; s.z += v.z; s.w += v.w;
    }
    *(float4*)&tmp[(size_t)y * (N_COMM * DIM_M) + idx4 * 4] = s;
}

__global__ __launch_bounds__(256) void k_comm2b(const float* __restrict__ tmp,
                                                float* __restrict__ out) {
    const int idx4 = blockIdx.x * 256 + threadIdx.x;
    float4 s = make_float4(0.f, 0.f, 0.f, 0.f);
    for (int y = 0; y < 32; ++y) {
        float4 v = *(const float4*)&tmp[(size_t)y * (N_COMM * DIM_M) + idx4 * 4];
        s.x += v.x; s.y += v.y; s.z += v.z; s.w += v.w;
    }
    const int q = idx4 >> 9;
    const int tid = idx4 & 511;
    const int ct = q >> 3, mt = q & 7;
    const int w = tid >> 6, l = tid & 63;
    const int lr = l & 15, lk = l >> 4;
    const int mm = mt * 16 + lr;
    const float sv[4] = {s.x, s.y, s.z, s.w};
#pragma unroll
    for (int reg = 0; reg < 4; ++reg) {
        const int cc = (w * 2 + ct) * 16 + lk * 4 + reg;
        out[(size_t)N_NODES * DIM_M + (size_t)cc * DIM_M + mm] = sv[reg];
    }
}

// ================= FALLBACK PATH (small ws) =================
__global__ __launch_bounds__(256) void k_wconv_old(const float* __restrict__ W_ih,
                                                   const float* __restrict__ W_hh,
                                                   unsigned short* __restrict__ Wt) {
    int idx = blockIdx.x * 256 + threadIdx.x;
    if (idx >= GCOLS * K_TOT) return;
    int col = idx / K_TOT, k = idx % K_TOT;
    float v;
    if (col < 256) {
        v = (k < 448) ? W_ih[(size_t)k * 384 + col]
                      : W_hh[(size_t)(k - 448) * 384 + col];
    } else if (col < 384) {
        v = (k < 448) ? W_ih[(size_t)k * 384 + col] : 0.0f;
    } else {
        v = (k < 448) ? 0.0f : W_hh[(size_t)(k - 448) * 384 + (col - 128)];
    }
    Wt[idx] = f2bf(v);
}

__global__ __launch_bounds__(256) void k_tenc(const unsigned long long* __restrict__ keys,
                                              const unsigned int* __restrict__ cnt,
                                              const int* __restrict__ list,
                                              const int* __restrict__ t,
                                              const int* __restrict__ last_update,
                                              const float* __restrict__ w_time,
                                              const float* __restrict__ b_time,
                                              unsigned short* __restrict__ tenc) {
    int idx = blockIdx.x * 256 + threadIdx.x;
    int r = idx >> 3, slot = idx & 7;
    const unsigned c = *cnt;
    const unsigned cpad = (c + 63u) & ~63u;
    if ((unsigned)r >= cpad) return;
    s16x8 v;
    if ((unsigned)r < c) {
        int node = list[r];
        unsigned long long key = keys[node];
        int ia = (int)(key & 0xffffffffull) - 1;
        int e = (ia < N_EVENTS) ? ia : ia - N_EVENTS;
        float dt = (float)(t[e] - last_update[node]);
#pragma unroll
        for (int j = 0; j < 8; ++j) {
            int cix = slot * 8 + j;
            float arg = __fadd_rn(__fmul_rn(dt, w_time[cix]), b_time[cix]);
            v[j] = (short)f2bf(cosf(arg));
        }
    } else {
#pragma unroll
        for (int j = 0; j < 8; ++j) v[j] = 0;
    }
    *(s16x8*)&tenc[(size_t)r * 64 + slot * 8] = v;
}

__global__ __launch_bounds__(256, 2) void k_gemm_fused(
    const unsigned long long* __restrict__ keys,
    const unsigned int* __restrict__ cnt,
    const int* __restrict__ list,
    const float* __restrict__ event_feat,
    const float* __restrict__ src_embeds,
    const float* __restrict__ dst_embeds,
    const float* __restrict__ mem,
    const unsigned short* __restrict__ tenc,
    const unsigned short* __restrict__ Wt,
    const float* __restrict__ b_ih,
    const float* __restrict__ b_hh,
    float* __restrict__ out) {
    __shared__ unsigned short Xs[2][4][64][8];

    const unsigned c = *cnt;
    const int base = blockIdx.x * 64;
    if ((unsigned)base >= c) return;
    const int tid = threadIdx.x;

    const int srow = tid >> 2;
    const int kslot = tid & 3;
    const int sgrow = base + srow;
    const bool valid = (unsigned)sgrow < c;
    const float *p_es = nullptr, *p_ed = nullptr, *p_ef = nullptr, *p_mem = nullptr;
    const unsigned short* p_te = nullptr;
    if (valid) {
        int node = list[sgrow];
        unsigned long long key = keys[node];
        int ia = (int)(key & 0xffffffffull) - 1;
        int e = (ia < N_EVENTS) ? ia : ia - N_EVENTS;
        const float* sp = src_embeds + (size_t)e * 128;
        const float* dp = dst_embeds + (size_t)e * 128;
        p_es = (ia < N_EVENTS) ? sp : dp;
        p_ed = (ia < N_EVENTS) ? dp : sp;
        p_ef = event_feat + (size_t)e * 128;
        p_te = tenc + (size_t)sgrow * 64;
        p_mem = mem + (size_t)node * 128;
    }

    auto stage = [&](int ch) {
        const int buf = ch & 1;
        const int k0 = ch * 32 + kslot * 8;
        s16x8 v;
        if (valid) {
            if (k0 < 384) {
                const float* p = (k0 < 128) ? (p_es + k0)
                               : (k0 < 256) ? (p_ed + (k0 - 128))
                                            : (p_ef + (k0 - 256));
                float4 a = *(const float4*)p;
                float4 b = *(const float4*)(p + 4);
                v = pack_bf8(a, b);
            } else if (k0 < 448) {
                v = *(const s16x8*)(p_te + (k0 - 384));
            } else {
                const float* p = p_mem + (k0 - 448);
                float4 a = *(const float4*)p;
                float4 b = *(const float4*)(p + 4);
                v = pack_bf8(a, b);
            }
        } else {
#pragma unroll
            for (int j = 0; j < 8; ++j) v[j] = 0;
        }
        *(s16x8*)&Xs[buf][kslot][srow][0] = v;
    };

    const int w = tid >> 6;
    const int l = tid & 63;
    const int lr = l & 15;
    const int lk = l >> 4;

    f32x4 acc[4][8];
#pragma unroll
    for (int rt = 0; rt < 4; ++rt)
#pragma unroll
        for (int i = 0; i < 8; ++i) acc[rt][i] = (f32x4){0.f, 0.f, 0.f, 0.f};

    stage(0);
    __syncthreads();

    for (int ch = 0; ch < 18; ++ch) {
        if (ch < 17) stage(ch + 1);
        const int buf = ch & 1;
        s16x8 a[4];
#pragma unroll
        for (int rt = 0; rt < 4; ++rt)
            a[rt] = *(const s16x8*)&Xs[buf][lk][rt * 16 + lr][0];
#pragma unroll
        for (int i = 0; i < 8; ++i) {
            const int col = (w + 4 * i) * 16 + lr;
            s16x8 b = *(const s16x8*)&Wt[(size_t)col * K_TOT + ch * 32 + lk * 8];
#pragma unroll
            for (int rt = 0; rt < 4; ++rt)
                acc[rt][i] = __builtin_amdgcn_mfma_f32_16x16x32_bf16(
                    a[rt], b, acc[rt][i], 0, 0, 0);
        }
        __syncthreads();
    }

#pragma unroll
    for (int jj = 0; jj < 2; ++jj) {
        const int mcol = (w + 4 * jj) * 16 + lr;
        const float b_r  = b_ih[mcol] + b_hh[mcol];
        const float b_z  = b_ih[128 + mcol] + b_hh[128 + mcol];
        const float b_xn = b_ih[256 + mcol];
        const float b_hn = b_hh[256 + mcol];
#pragma unroll
        for (int rt = 0; rt < 4; ++rt) {
#pragma unroll
            for (int reg = 0; reg < 4; ++reg) {
                const int grow = base + rt * 16 + lk * 4 + reg;
                if ((unsigned)grow < c) {
                    const int node = list[grow];
                    const float h = mem[(size_t)node * 128 + mcol];
                    float rr = sigmoid_f(acc[rt][0 + jj][reg] + b_r);
                    float zz = sigmoid_f(acc[rt][2 + jj][reg] + b_z);
                    float nn = tanh_f(acc[rt][4 + jj][reg] + b_xn +
                                      rr * (acc[rt][6 + jj][reg] + b_hn));
                    out[(size_t)node * 128 + mcol] = (1.0f - zz) * nn + zz * h;
                }
            }
        }
    }
}

__global__ __launch_bounds__(256) void k_comm1(const float* __restrict__ inc,
                                               const float* __restrict__ nm,
                                               float* __restrict__ partials,
                                               int nch, int cpn) {
    __shared__ float inc_s[2][8][128];
    __shared__ float mem_s[2][8][128];

    const int bid = blockIdx.x;
    const int ct2 = bid / nch;
    const int ch  = bid % nch;
    const int n0 = ch * cpn;
    const int n1 = min(N_NODES, n0 + cpn);
    const int tid = threadIdx.x;

    const int srow = tid >> 5;
    const int scol = (tid & 31) * 4;

    auto stage = [&](int g, int buf) {
        const int n = n0 + g * 8 + srow;
        float4 iv = make_float4(0.f, 0.f, 0.f, 0.f);
        float4 mv = make_float4(0.f, 0.f, 0.f, 0.f);
        if (n < n1) {
            iv = *(const float4*)(inc + (size_t)n * N_COMM + ct2 * 128 + scol);
            mv = *(const float4*)(nm + (size_t)n * DIM_M + scol);
        }
        *(float4*)&inc_s[buf][srow][scol] = iv;
        *(float4*)&mem_s[buf][srow][scol] = mv;
    };

    const int c0 = (tid >> 3) * 4;
    const int mb = (tid & 7) * 4;

    float acc[4][4][4];
#pragma unroll
    for (int a = 0; a < 4; ++a)
#pragma unroll
        for (int b = 0; b < 4; ++b)
#pragma unroll
            for (int d = 0; d < 4; ++d) acc[a][b][d] = 0.0f;

    const int ngrp = (n1 - n0 + 7) >> 3;
    stage(0, 0);
    __syncthreads();

    for (int g = 0; g < ngrp; ++g) {
        if (g + 1 < ngrp) stage(g + 1, (g + 1) & 1);
        const int buf = g & 1;
#pragma unroll
        for (int i = 0; i < 8; ++i) {
            const float4 cv = *(const float4*)&inc_s[buf][i][c0];
            const float ca[4] = {cv.x, cv.y, cv.z, cv.w};
#pragma unroll
            for (int j = 0; j < 4; ++j) {
                const float4 mv = *(const float4*)&mem_s[buf][i][j * 32 + mb];
                const float ma[4] = {mv.x, mv.y, mv.z, mv.w};
#pragma unroll
                for (int ci = 0; ci < 4; ++ci)
#pragma unroll
                    for (int mi = 0; mi < 4; ++mi)
                        acc[ci][j][mi] = fmaf(ca[ci], ma[mi], acc[ci][j][mi]);
            }
        }
        __syncthreads();
    }

    float* p = partials + (size_t)bid * (128 * 128);
#pragma unroll
    for (int ci = 0; ci < 4; ++ci)
#pragma unroll
        for (int j = 0; j < 4; ++j)
            *(float4*)(p + (size_t)(c0 + ci) * 128 + j * 32 + mb) =
                make_float4(acc[ci][j][0], acc[ci][j][1], acc[ci][j][2], acc[ci][j][3]);
}

__global__ __launch_bounds__(256) void k_comm2_f(const float* __restrict__ partials,
                                                 float* __restrict__ out,
                                                 int nch) {
    int idx = blockIdx.x * 256 + threadIdx.x;
    if (idx >= N_COMM * DIM_M) return;
    int cg = idx >> 7;
    int m = idx & 127;
    int ct2 = cg >> 7;
    int cl = cg & 127;
    float s = 0.0f;
    for (int ch = 0; ch < nch; ++ch)
        s += partials[((size_t)ct2 * nch + ch) * 16384 + (size_t)cl * 128 + m];
    out[(size_t)N_NODES * DIM_M + idx] = s;
}

extern "C" void kernel_launch(void* const* d_in, const int* in_sizes, int n_in,
                              void* d_out, int out_size, void* d_ws, size_t ws_size,
                              hipStream_t stream) {
    const int* src          = (const int*)d_in[0];
    const int* dst          = (const int*)d_in[1];
    const int* t            = (const int*)d_in[2];
    const int* last_update  = (const int*)d_in[3];
    const float* event_feat = (const float*)d_in[4];
    const float* src_embeds = (const float*)d_in[5];
    const float* dst_embeds = (const float*)d_in[6];
    const float* nodes_mem  = (const float*)d_in[7];
    const float* incidence  = (const float*)d_in[8];
    const float* w_time     = (const float*)d_in[9];
    const float* b_time     = (const float*)d_in[10];
    const float* W_ih       = (const float*)d_in[11];
    const float* W_hh       = (const float*)d_in[12];
    const float* b_ih       = (const float*)d_in[13];
    const float* b_hh       = (const float*)d_in[14];
    float* out = (float*)d_out;

    char* ws = (char*)d_ws;
    unsigned long long* keys = (unsigned long long*)(ws + KEYS_OFF);
    unsigned int* cnt        = (unsigned int*)(ws + CNT_OFF);
    int* list                = (int*)(ws + LIST_OFF);
    int4* einfo              = (int4*)(ws + EINFO_OFF);

    const bool xfit = ws_size >= (size_t)X_OFF + (size_t)X_ROWS * (K_TOT * 2);

    unsigned* bcount = (unsigned*)(ws + (xfit ? BCNT_OFF : BCNT_F_OFF));
    unsigned* boff   = (unsigned*)(ws + (xfit ? BOFF_OFF : BOFF_F_OFF));

    hipMemsetAsync(d_ws, 0, LIST_OFF, stream);  // keys + cnt

    k_agg<<<(2 * N_EVENTS + 255) / 256, 256, 0, stream>>>(src, dst, t, keys);
    k_flag<<<NBLK, 256, 0, stream>>>(src, dst, keys, bcount);
    k_scan<<<1, 512, 0, stream>>>(bcount, boff, cnt);
    k_emit<<<NBLK, 256, 0, stream>>>(src, dst, t, last_update, keys, boff,
                                     list, einfo);

    if (xfit) {
        unsigned short* Wt = (unsigned short*)(ws + WT_OFF);
        unsigned short* X  = (unsigned short*)(ws + X_OFF);
        float* partials    = (float*)(ws + PART_M_OFF);
        float* tmp2        = (float*)(ws + TMP2_OFF);

        k_xbuild<<<XB_GRID + WCONV_BLOCKS + COPY_BLOCKS, 256, 0, stream>>>(
            keys, cnt, einfo, event_feat, src_embeds, dst_embeds,
            nodes_mem, w_time, b_time, W_ih, W_hh, Wt, X, out);
        k_gemm2<<<(X_ROWS / 128) * 2, 512, 0, stream>>>(cnt, list, X, Wt,
                                                        b_ih, b_hh, out);
        k_comm_t<<<CT_NCH, 512, 0, stream>>>(incidence, out, partials);
        k_comm2a<<<1024, 256, 0, stream>>>(partials, tmp2);
        k_comm2b<<<32, 256, 0, stream>>>(tmp2, out);
    } else {
        unsigned short* Wt   = (unsigned short*)(ws + WT_F_OFF);
        unsigned short* tenc = (unsigned short*)(ws + TENC_OFF);
        float* partials      = (float*)(ws + PART_F_OFF);
        int NCH = 512;
        while (NCH > 8 && (size_t)PART_F_OFF + (size_t)NCH * 131072 > ws_size) NCH >>= 1;
        int cpn = (N_NODES + NCH - 1) / NCH;

        k_wconv_old<<<(GCOLS * K_TOT + 255) / 256, 256, 0, stream>>>(W_ih, W_hh, Wt);
        k_tenc<<<(100032 * 8) / 256, 256, 0, stream>>>(keys, cnt, list, t, last_update,
                                                       w_time, b_time, tenc);
        k_gemm_fused<<<100032 / 64, 256, 0, stream>>>(keys, cnt, list, event_feat,
                                                      src_embeds, dst_embeds, nodes_mem,
                                                      tenc, Wt, b_ih, b_hh, out);
        k_copy<<<(N_NODES * 32 + 255) / 256, 256, 0, stream>>>(keys, nodes_mem, out);
        k_comm1<<<2 * NCH, 256, 0, stream>>>(incidence, out, partials, NCH, cpn);
        k_comm2_f<<<(N_COMM * DIM_M + 255) / 256, 256, 0, stream>>>(partials, out, NCH);
    }
}